// Round 17
// baseline (142.142 us; speedup 1.0000x reference)
//
#include <hip/hip_runtime.h>
#include <math.h>

#define TT 2048
#define LK 769
#define NF 20
#define NS 128
#define NB 18

typedef __attribute__((ext_vector_type(8))) short short8;
typedef __attribute__((ext_vector_type(4))) float f32x4;

// ---------------------------------------------------------------------------
// Kernel P: one-time prep (unchanged from R16): twiddles + symmetrized
// filters + 8-aligned nonzero ranges.
// ---------------------------------------------------------------------------
__global__ __launch_bounds__(256) void prep_kernel(const float* __restrict__ ker,
                                                   float2* __restrict__ tw,
                                                   float* __restrict__ hsym,
                                                   int* __restrict__ rng) {
  __shared__ int red[4][2];
  const int blk = blockIdx.x;
  const int tid = threadIdx.x;
  if (blk < 8) {
    int i = blk * 256 + tid;
    if (i == 0) { tw[0] = make_float2(1.f, 0.f); }
    else {
      int half = 1 << (31 - __clz(i));
      int j = i - half;
      float ang = -3.14159265358979323846f * (float)j / (float)half;
      float s, c;
      sincosf(ang, &s, &c);
      tw[i] = make_float2(c, s);
    }
    return;
  }
  const int o = blk - 8;
  const float* kr = ker + o * LK;
  int k0 = 784, k1 = 0;
  for (int k = tid; k < 784; k += 256) {
    float v = 0.f;
    if (k < LK) v = 0.5f * (kr[k] + kr[LK - 1 - k]);
    hsym[o * 784 + k] = v;
    if (v != 0.f) { k0 = min(k0, k); k1 = max(k1, k + 1); }
  }
#pragma unroll
  for (int off = 32; off > 0; off >>= 1) {
    k0 = min(k0, __shfl_down(k0, off));
    k1 = max(k1, __shfl_down(k1, off));
  }
  if ((tid & 63) == 0) { red[tid >> 6][0] = k0; red[tid >> 6][1] = k1; }
  __syncthreads();
  if (tid == 0) {
    k0 = min(min(red[0][0], red[1][0]), min(red[2][0], red[3][0]));
    k1 = max(max(red[0][1], red[1][1]), max(red[2][1], red[3][1]));
    rng[2 * o] = k0 & ~7;              // 8-aligned (extra taps exact zeros)
    rng[2 * o + 1] = (k1 + 7) & ~7;
  }
}

__device__ __forceinline__ void split3(float v, unsigned short& h,
                                       unsigned short& m, unsigned short& l) {
  unsigned int u = __float_as_uint(v);
  float hf = __uint_as_float(u & 0xFFFF0000u);
  float r1 = v - hf;                        // exact
  unsigned int u2 = __float_as_uint(r1);
  float mf = __uint_as_float(u2 & 0xFFFF0000u);
  float r2 = r1 - mf;                       // exact
  unsigned int u3 = __float_as_uint(r2);
  h = (unsigned short)(u >> 16);
  m = (unsigned short)(u2 >> 16);
  l = (unsigned short)(u3 >> 16);
}

// ---------------------------------------------------------------------------
// Kernel A: FUSED conv + Hilbert (R16 structure). R17: the epilogue emits
// mi-ready formats straight from registers — packed uint8 phase-bin indices
// and 3-way-split bf16 amp rows (same expressions on the same fp32 register
// values as mi previously computed -> bit-identical). fp32 filt rows are no
// longer written (nothing reads them).
// ---------------------------------------------------------------------------
__global__ __launch_bounds__(256) void convhil_kernel(const float* __restrict__ x,
                                                      const float* __restrict__ hsym,
                                                      const int* __restrict__ rng,
                                                      const float2* __restrict__ tw,
                                                      unsigned short* __restrict__ asH,
                                                      unsigned short* __restrict__ asM,
                                                      unsigned short* __restrict__ asL,
                                                      unsigned char* __restrict__ idx8) {
  __shared__ __align__(16) float smem[4400];   // w[2832]+hs1[784]+hs2[784]; z overlays
  float* w   = smem;
  float* hs1 = smem + 2832;
  float* hs2 = smem + 3616;
  float2* z  = (float2*)smem;                  // 2048 float2 = 4096 floats < 4400
  const int tid = threadIdx.x;
  const int ord = blockIdx.x;
  const int p = ord / NS;                   // 0..9, longest pair first
  const int n = ord % NS;
  const int o1 = p;                          // pha band
  const int o2 = 10 + (9 - p);               // amp band (short with long)
  const float* xr = x + n * TT;
  for (int j = tid; j < 2832; j += 256) {
    float v = 0.f;
    if (j < 2816) {
      int m = j - 384;              // spad[j+384] -> original index (j+384)-768
      if (m < 0) m = -m;            // reflect (edge excluded)
      if (m > 2047) m = 4094 - m;
      v = xr[m];
    }
    w[j] = v;
  }
  const float* h1g = hsym + o1 * 784;
  const float* h2g = hsym + o2 * 784;
  for (int k = tid; k < 784; k += 256) {
    hs1[k] = h1g[k];
    hs2[k] = h2g[k];
  }
  const int A0 = rng[2 * o1], A1 = rng[2 * o1 + 1];   // uniform -> scalar loads
  const int B0 = rng[2 * o2], B1 = rng[2 * o2 + 1];
  const int U0 = min(A0, B0);
  const int U1 = max(A1, B1);
  __syncthreads();

  const int bA = 4 * tid;           // group A outputs [bA, bA+4)
  const int bB = 1024 + 4 * tid;    // group B outputs [bB, bB+4)
  float acc1A[4], acc1B[4], acc2A[4], acc2B[4];
#pragma unroll
  for (int r = 0; r < 4; ++r) { acc1A[r] = 0.f; acc1B[r] = 0.f; acc2A[r] = 0.f; acc2B[r] = 0.f; }
  if (U0 < U1) {
    // rolling window: a0..a2 cover w[bA+k .. bA+k+12)
    float4 a0 = *(const float4*)&w[bA + U0];
    float4 a1 = *(const float4*)&w[bA + U0 + 4];
    float4 a2 = *(const float4*)&w[bA + U0 + 8];
    float4 b0 = *(const float4*)&w[bB + U0];
    float4 b1 = *(const float4*)&w[bB + U0 + 4];
    float4 b2 = *(const float4*)&w[bB + U0 + 8];
    float4 h1a = *(const float4*)&hs1[U0];
    float4 h1b = *(const float4*)&hs1[U0 + 4];
    float4 h2a = *(const float4*)&hs2[U0];
    float4 h2b = *(const float4*)&hs2[U0 + 4];
    for (int k = U0; k < U1; k += 8) {
      float4 a3 = *(const float4*)&w[bA + k + 12];
      float4 a4 = *(const float4*)&w[bA + k + 16];
      float4 b3 = *(const float4*)&w[bB + k + 12];
      float4 b4 = *(const float4*)&w[bB + k + 16];
      float4 h1an = *(const float4*)&hs1[k + 8];
      float4 h1bn = *(const float4*)&hs1[k + 12];
      float4 h2an = *(const float4*)&hs2[k + 8];
      float4 h2bn = *(const float4*)&hs2[k + 12];
      float wa[11] = {a0.x, a0.y, a0.z, a0.w, a1.x, a1.y, a1.z, a1.w,
                      a2.x, a2.y, a2.z};
      float wb[11] = {b0.x, b0.y, b0.z, b0.w, b1.x, b1.y, b1.z, b1.w,
                      b2.x, b2.y, b2.z};
      float h1[8] = {h1a.x, h1a.y, h1a.z, h1a.w, h1b.x, h1b.y, h1b.z, h1b.w};
      float h2[8] = {h2a.x, h2a.y, h2a.z, h2a.w, h2b.x, h2b.y, h2b.z, h2b.w};
      if (k >= A0 && k < A1) {
#pragma unroll
        for (int r = 0; r < 4; ++r) {
#pragma unroll
          for (int j = 0; j < 8; ++j) {
            acc1A[r] = fmaf(h1[j], wa[r + j], acc1A[r]);
            acc1B[r] = fmaf(h1[j], wb[r + j], acc1B[r]);
          }
        }
      }
      if (k >= B0 && k < B1) {
#pragma unroll
        for (int r = 0; r < 4; ++r) {
#pragma unroll
          for (int j = 0; j < 8; ++j) {
            acc2A[r] = fmaf(h2[j], wa[r + j], acc2A[r]);
            acc2B[r] = fmaf(h2[j], wb[r + j], acc2B[r]);
          }
        }
      }
      a0 = a2; a1 = a3; a2 = a4;
      b0 = b2; b1 = b3; b2 = b4;
      h1a = h1an; h1b = h1bn;
      h2a = h2an; h2b = h2bn;
    }
  }
  // ---- hand off to FFT: z = out1 + i*out2 (overlays dead w/hs region) ----
  __syncthreads();                    // everyone done reading w/hs
#pragma unroll
  for (int r = 0; r < 4; ++r) {
    z[bA + r] = make_float2(acc1A[r], acc2A[r]);
    z[bB + r] = make_float2(acc1B[r], acc2B[r]);
  }
  __syncthreads();
  // ---- forward radix-2 DIF stage (half=1024) ----
  for (int bf = tid; bf < 1024; bf += 256) {
    const float2 t = tw[1024 + bf];
    const float2 u = z[bf];
    const float2 v = z[bf + 1024];
    z[bf] = make_float2(u.x + v.x, u.y + v.y);
    const float dr = u.x - v.x, di = u.y - v.y;
    z[bf + 1024] = make_float2(fmaf(t.x, dr, -(t.y * di)),
                               fmaf(t.x, di, t.y * dr));
  }
  __syncthreads();
  // ---- forward radix-4 DIF stages: Q = 256,64,16,4,1 ----
  for (int Q = 256; Q >= 1; Q >>= 2) {
    for (int bf = tid; bf < 512; bf += 256) {
      const int j = bf & (Q - 1);
      const int base = ((bf & ~(Q - 1)) << 2) + j;
      const float2 x0 = z[base], x1 = z[base + Q];
      const float2 x2 = z[base + 2 * Q], x3 = z[base + 3 * Q];
      const float2 w1 = tw[2 * Q + j];
      const float2 w2 = tw[Q + j];
      const float w3r = w1.x * w2.x - w1.y * w2.y;
      const float w3i = w1.x * w2.y + w1.y * w2.x;
      const float t0r = x0.x + x2.x, t0i = x0.y + x2.y;
      const float t1r = x0.x - x2.x, t1i = x0.y - x2.y;
      const float t2r = x1.x + x3.x, t2i = x1.y + x3.y;
      const float t3r = x1.x - x3.x, t3i = x1.y - x3.y;
      z[base] = make_float2(t0r + t2r, t0i + t2i);
      const float a1r = t1r + t3i, a1i = t1i - t3r;     // (t1 - i t3)
      z[base + Q] = make_float2(a1r * w1.x - a1i * w1.y,
                                a1r * w1.y + a1i * w1.x);
      const float a2r = t0r - t2r, a2i = t0i - t2i;
      z[base + 2 * Q] = make_float2(a2r * w2.x - a2i * w2.y,
                                    a2r * w2.y + a2i * w2.x);
      const float a3r = t1r - t3i, a3i = t1i + t3r;     // (t1 + i t3)
      z[base + 3 * Q] = make_float2(a3r * w3r - a3i * w3i,
                                    a3r * w3i + a3i * w3r);
    }
    __syncthreads();
  }
  // ---- Hilbert mask in mixed-digit-reversed space ----
  for (int pp = tid; pp < TT; pp += 256) {
    if (pp != 0 && pp != 2) {
      if (pp & 2) { z[pp] = make_float2(0.f, 0.f); }
      else        { float2 v = z[pp]; z[pp] = make_float2(2.f * v.x, 2.f * v.y); }
    }
  }
  __syncthreads();
  // ---- inverse radix-4 DIT stages: Q = 1,4,16,64,256 (conj twiddles) ----
  for (int Q = 1; Q <= 256; Q <<= 2) {
    for (int bf = tid; bf < 512; bf += 256) {
      const int j = bf & (Q - 1);
      const int base = ((bf & ~(Q - 1)) << 2) + j;
      const float2 y0 = z[base], y1 = z[base + Q];
      const float2 y2 = z[base + 2 * Q], y3 = z[base + 3 * Q];
      const float2 w1 = tw[2 * Q + j];
      const float2 w2 = tw[Q + j];
      const float w3r = w1.x * w2.x - w1.y * w2.y;
      const float w3i = w1.x * w2.y + w1.y * w2.x;
      // u_m = y_m * conj(w_m)
      const float u1r = y1.x * w1.x + y1.y * w1.y;
      const float u1i = y1.y * w1.x - y1.x * w1.y;
      const float u2r = y2.x * w2.x + y2.y * w2.y;
      const float u2i = y2.y * w2.x - y2.x * w2.y;
      const float u3r = y3.x * w3r + y3.y * w3i;
      const float u3i = y3.y * w3r - y3.x * w3i;
      const float t0r = y0.x + u2r, t0i = y0.y + u2i;
      const float t1r = y0.x - u2r, t1i = y0.y - u2i;
      const float t2r = u1r + u3r, t2i = u1i + u3i;
      const float t3r = u1r - u3r, t3i = u1i - u3i;
      z[base]         = make_float2(t0r + t2r, t0i + t2i);
      z[base + Q]     = make_float2(t1r - t3i, t1i + t3r);  // t1 + i t3
      z[base + 2 * Q] = make_float2(t0r - t2r, t0i - t2i);
      z[base + 3 * Q] = make_float2(t1r + t3i, t1i - t3r);  // t1 - i t3
    }
    __syncthreads();
  }
  // ---- inverse radix-2 DIT stage (half=1024, conj twiddle) ----
  for (int bf = tid; bf < 1024; bf += 256) {
    const float2 t = tw[1024 + bf];
    const float2 u = z[bf];
    const float2 v = z[bf + 1024];
    const float vr = v.x * t.x + v.y * t.y;
    const float vi = v.y * t.x - v.x * t.y;
    z[bf] = make_float2(u.x + vr, u.y + vi);
    z[bf + 1024] = make_float2(u.x - vr, u.y - vi);
  }
  __syncthreads();
  // ---- epilogue: bins (phase band p) + 3-way-split bf16 amp (band 9-p) ----
  const float invN = 1.0f / 2048.0f;
  const size_t ibase = ((size_t)n * 10 + p) * TT;
  const size_t abase = ((size_t)n * 10 + (9 - p)) * TT;
#pragma unroll
  for (int g = 0; g < 2; ++g) {
    const int base = g ? bB : bA;
    const float* a1 = g ? acc1B : acc1A;
    const float* a2 = g ? acc2B : acc2A;
    unsigned int binpack = 0;
    unsigned short hh[4], mm[4], ll[4];
#pragma unroll
    for (int r = 0; r < 4; ++r) {
      float2 wv = z[base + r];
      float h1 = wv.y * invN - a2[r];
      float h2 = a1[r] - wv.x * invN;
      float ph = atan2f(h1, a1[r]);
      float am = sqrtf(fmaf(a2[r], a2[r], h2 * h2));
      int b = (int)floorf((ph + 3.14159274f) / 6.2831855f * 18.0f);
      b = b < 0 ? 0 : (b > 17 ? 17 : b);
      binpack |= ((unsigned int)b) << (8 * r);
      split3(am, hh[r], mm[r], ll[r]);
    }
    *(unsigned int*)(idx8 + ibase + base) = binpack;
    uint2 ph2, pm2, pl2;
    ph2.x = (unsigned int)hh[0] | ((unsigned int)hh[1] << 16);
    ph2.y = (unsigned int)hh[2] | ((unsigned int)hh[3] << 16);
    pm2.x = (unsigned int)mm[0] | ((unsigned int)mm[1] << 16);
    pm2.y = (unsigned int)mm[2] | ((unsigned int)mm[3] << 16);
    pl2.x = (unsigned int)ll[0] | ((unsigned int)ll[1] << 16);
    pl2.y = (unsigned int)ll[2] | ((unsigned int)ll[3] << 16);
    *(uint2*)(asH + abase + base) = ph2;
    *(uint2*)(asM + abase + base) = pm2;
    *(uint2*)(asL + abase + base) = pl2;
  }
}

// ---------------------------------------------------------------------------
// Kernel C: binned MI via MFMA, R17: A-fragments loaded directly as
// pre-split bf16 (producer-side formatting in convhil) and bin indices as
// packed bytes -> the ~230 cyc/step repack is gone (~70 cyc/step remain).
// 4 waves/block K-split, verified 16x16x32 layouts, bit-identical sums.
// ---------------------------------------------------------------------------
__global__ __launch_bounds__(256) void mi_kernel(const unsigned short* __restrict__ asH,
                                                 const unsigned short* __restrict__ asM,
                                                 const unsigned short* __restrict__ asL,
                                                 const unsigned char* __restrict__ idx8,
                                                 float* __restrict__ mi) {
  __shared__ float Cp[4][12][19];                    // per-wave partial C
  const int tid = threadIdx.x;
  const int wave = tid >> 6;
  const int lane = tid & 63;
  const int blk = blockIdx.x;           // bc*40 + jp
  const int bc = blk / 40, jp = blk % 40;
  const int n16 = lane & 15;    // A row m / B col n / C col
  const int quad = lane >> 4;   // k-quad (0..3)
  const int aband = n16 < 10 ? n16 : 9;
  const int ja = (jp & 3) + 4 * aband;   // scrambled amp row, same s'
  const size_t arow = (size_t)((bc * 4 + ja / 10) * 10 + (ja % 10)) * TT + quad * 8;
  const size_t prow = (size_t)((bc * 4 + jp / 10) * 10 + (jp % 10)) * TT;
  const unsigned char* ib = idx8 + prow + quad * 8;
  const bool isAmp = (n16 < 10);
  const bool isOne = (n16 == 10);
  f32x4 acc0 = {0.f, 0.f, 0.f, 0.f};     // bins 0..15
  f32x4 acc1 = {0.f, 0.f, 0.f, 0.f};     // bins 16..17 (cols 16+n16)
  const int s0 = wave * 16, s1 = s0 + 16;
#pragma unroll 4
  for (int s = s0; s < s1; ++s) {
    const size_t o = arow + (size_t)s * 32;
    short8 ah = *(const short8*)(asH + o);
    short8 am_ = *(const short8*)(asM + o);
    short8 al = *(const short8*)(asL + o);
    if (!isAmp) {
      const short ov = isOne ? (short)0x3F80 : (short)0;
#pragma unroll
      for (int j = 0; j < 8; ++j) { ah[j] = ov; am_[j] = 0; al[j] = 0; }
    }
    const uint2 d = *(const uint2*)(ib + s * 32);
    const unsigned int d0 = d.x, d1 = d.y;
    short8 b0, b1;
#pragma unroll
    for (int j = 0; j < 8; ++j) {
      unsigned int byte = ((j < 4 ? d0 : d1) >> ((j & 3) * 8)) & 0xFFu;
      b0[j] = (byte == (unsigned int)n16) ? (short)0x3F80 : (short)0;
      b1[j] = (byte == (unsigned int)(n16 + 16)) ? (short)0x3F80 : (short)0;
    }
    acc0 = __builtin_amdgcn_mfma_f32_16x16x32_bf16(ah, b0, acc0, 0, 0, 0);
    acc0 = __builtin_amdgcn_mfma_f32_16x16x32_bf16(am_, b0, acc0, 0, 0, 0);
    acc0 = __builtin_amdgcn_mfma_f32_16x16x32_bf16(al, b0, acc0, 0, 0, 0);
    acc1 = __builtin_amdgcn_mfma_f32_16x16x32_bf16(ah, b1, acc1, 0, 0, 0);
    acc1 = __builtin_amdgcn_mfma_f32_16x16x32_bf16(am_, b1, acc1, 0, 0, 0);
    acc1 = __builtin_amdgcn_mfma_f32_16x16x32_bf16(al, b1, acc1, 0, 0, 0);
  }
#pragma unroll
  for (int r = 0; r < 4; ++r) {
    int row = quad * 4 + r;
    if (row < 11) {
      Cp[wave][row][n16] = acc0[r];
      if (n16 < 2) Cp[wave][row][16 + n16] = acc1[r];
    }
  }
  __syncthreads();
  if (tid < 10) {
    float tot = 0.f, mb_[18];
#pragma unroll
    for (int b = 0; b < 18; ++b) {
      float s = Cp[0][tid][b] + Cp[1][tid][b] + Cp[2][tid][b] + Cp[3][tid][b];
      float c = Cp[0][10][b] + Cp[1][10][b] + Cp[2][10][b] + Cp[3][10][b];
      float mb = s / fmaxf(c, 1.0f);
      mb_[b] = mb; tot += mb;
    }
    tot = fmaxf(tot, 1e-12f);
    float s = 0.f;
#pragma unroll
    for (int b = 0; b < 18; ++b) {
      float pb = mb_[b] / tot;
      s += pb * logf(fmaxf(pb, 1e-12f));
    }
    const float LOGN = 2.8903717578961645f; // log(18)
    mi[(size_t)blk * 10 + tid] = (LOGN + s) / LOGN;
  }
}

// ---------------------------------------------------------------------------
// Kernel D: mean over the scrambled s' axis -> out (4,8,10,10)
// ---------------------------------------------------------------------------
__global__ void out_kernel(const float* __restrict__ mi, float* __restrict__ out) {
  int i = blockIdx.x * 256 + threadIdx.x;
  if (i < 3200) {
    int a = i % 10, p = (i / 10) % 10, bc = i / 100;
    float s = 0.f;
    for (int sp = 0; sp < 4; ++sp)
      s += mi[((size_t)(bc * 40 + p * 4 + sp)) * 10 + a];
    out[i] = 0.25f * s;
  }
}

extern "C" void kernel_launch(void* const* d_in, const int* in_sizes, int n_in,
                              void* d_out, int out_size, void* d_ws, size_t ws_size,
                              hipStream_t stream) {
  (void)in_sizes; (void)n_in; (void)out_size; (void)ws_size;
  const float* x = (const float*)d_in[0];     // (4,8,4,2048) fp32
  const float* ker = (const float*)d_in[1];   // (20,769) fp32
  float* out = (float*)d_out;                 // 3200 fp32

  float* mi = (float*)d_ws;                   // 12800 fp32
  float2* tw = (float2*)(mi + 12800);         // 2048 float2 (16 KB)
  float* hsym = (float*)(tw + TT);            // 20*784 fp32
  int* rng = (int*)(hsym + NF * 784);         // 40 ints
  unsigned short* asH = (unsigned short*)(rng + 40);   // 128*10*2048 u16
  unsigned short* asM = asH + (size_t)NS * 10 * TT;
  unsigned short* asL = asM + (size_t)NS * 10 * TT;
  unsigned char* idx8 = (unsigned char*)(asL + (size_t)NS * 10 * TT); // 128*10*2048 u8

  prep_kernel<<<28, 256, 0, stream>>>(ker, tw, hsym, rng);
  convhil_kernel<<<NS * 10, 256, 0, stream>>>(x, hsym, rng, tw, asH, asM, asL, idx8);
  mi_kernel<<<32 * 40, 256, 0, stream>>>(asH, asM, asL, idx8, mi);
  out_kernel<<<(3200 + 255) / 256, 256, 0, stream>>>(mi, out);
}

// Round 18
// 134.256 us; speedup vs baseline: 1.0587x; 1.0587x over previous
//
#include <hip/hip_runtime.h>
#include <math.h>

#define TT 2048
#define LK 769
#define NF 20
#define NS 128
#define NB 18

typedef __attribute__((ext_vector_type(8))) short short8;
typedef __attribute__((ext_vector_type(4))) float f32x4;

__device__ __forceinline__ float2 cmul(float2 a, float2 b) {
  return make_float2(a.x * b.x - a.y * b.y, a.x * b.y + a.y * b.x);
}
__device__ __forceinline__ float2 cmulc(float2 a, float2 b) {  // a * conj(b)
  return make_float2(a.x * b.x + a.y * b.y, a.y * b.x - a.x * b.y);
}
#define CADD(a, b) make_float2((a).x + (b).x, (a).y + (b).y)
#define CSUB(a, b) make_float2((a).x - (b).x, (a).y - (b).y)

// ---------------------------------------------------------------------------
// Kernel P: one-time prep (unchanged from R16): twiddles + symmetrized
// filters + 8-aligned nonzero ranges.
// ---------------------------------------------------------------------------
__global__ __launch_bounds__(256) void prep_kernel(const float* __restrict__ ker,
                                                   float2* __restrict__ tw,
                                                   float* __restrict__ hsym,
                                                   int* __restrict__ rng) {
  __shared__ int red[4][2];
  const int blk = blockIdx.x;
  const int tid = threadIdx.x;
  if (blk < 8) {
    int i = blk * 256 + tid;
    if (i == 0) { tw[0] = make_float2(1.f, 0.f); }
    else {
      int half = 1 << (31 - __clz(i));
      int j = i - half;
      float ang = -3.14159265358979323846f * (float)j / (float)half;
      float s, c;
      sincosf(ang, &s, &c);
      tw[i] = make_float2(c, s);
    }
    return;
  }
  const int o = blk - 8;
  const float* kr = ker + o * LK;
  int k0 = 784, k1 = 0;
  for (int k = tid; k < 784; k += 256) {
    float v = 0.f;
    if (k < LK) v = 0.5f * (kr[k] + kr[LK - 1 - k]);
    hsym[o * 784 + k] = v;
    if (v != 0.f) { k0 = min(k0, k); k1 = max(k1, k + 1); }
  }
#pragma unroll
  for (int off = 32; off > 0; off >>= 1) {
    k0 = min(k0, __shfl_down(k0, off));
    k1 = max(k1, __shfl_down(k1, off));
  }
  if ((tid & 63) == 0) { red[tid >> 6][0] = k0; red[tid >> 6][1] = k1; }
  __syncthreads();
  if (tid == 0) {
    k0 = min(min(red[0][0], red[1][0]), min(red[2][0], red[3][0]));
    k1 = max(max(red[0][1], red[1][1]), max(red[2][1], red[3][1]));
    rng[2 * o] = k0 & ~7;              // 8-aligned (extra taps exact zeros)
    rng[2 * o + 1] = (k1 + 7) & ~7;
  }
}

// ---------------------------------------------------------------------------
// Kernel A: FUSED conv + Hilbert (R16 structure). R18: FFT factored as
// 8*8*8*4 — forward 3x radix-8 DIF (Q=256,32,4) + radix-4 (Q=1), inverse
// mirrored with conj twiddles. Barrier-separated stages 13 -> 9, FFT DS
// ops -33%. Digit-reversal: k=(e1,e2,e3;e4) -> p=e1*256+e2*32+e3*4+e4,
// bit10(k) = (p&2), so the Hilbert mask rule is unchanged:
// p==0,p==2 -> x1; (p&2)==0 -> x2; else 0.
// Twiddles: W_{8Q}^j = tw[4Q+j], ^2j = tw[2Q+j], ^4j = tw[Q+j]; others by
// complex products.
// ---------------------------------------------------------------------------
__global__ __launch_bounds__(256) void convhil_kernel(const float* __restrict__ x,
                                                      const float* __restrict__ hsym,
                                                      const int* __restrict__ rng,
                                                      const float2* __restrict__ tw,
                                                      float* __restrict__ filt) {
  __shared__ __align__(16) float smem[4400];   // w[2832]+hs1[784]+hs2[784]; z overlays
  float* w   = smem;
  float* hs1 = smem + 2832;
  float* hs2 = smem + 3616;
  float2* z  = (float2*)smem;                  // 2048 float2 = 4096 floats < 4400
  const int tid = threadIdx.x;
  const int ord = blockIdx.x;
  const int p = ord / NS;                   // 0..9, longest pair first
  const int n = ord % NS;
  const int o1 = p;                          // pha band
  const int o2 = 10 + (9 - p);               // amp band (short with long)
  const float* xr = x + n * TT;
  for (int j = tid; j < 2832; j += 256) {
    float v = 0.f;
    if (j < 2816) {
      int m = j - 384;              // spad[j+384] -> original index (j+384)-768
      if (m < 0) m = -m;            // reflect (edge excluded)
      if (m > 2047) m = 4094 - m;
      v = xr[m];
    }
    w[j] = v;
  }
  const float* h1g = hsym + o1 * 784;
  const float* h2g = hsym + o2 * 784;
  for (int k = tid; k < 784; k += 256) {
    hs1[k] = h1g[k];
    hs2[k] = h2g[k];
  }
  const int A0 = rng[2 * o1], A1 = rng[2 * o1 + 1];   // uniform -> scalar loads
  const int B0 = rng[2 * o2], B1 = rng[2 * o2 + 1];
  const int U0 = min(A0, B0);
  const int U1 = max(A1, B1);
  __syncthreads();

  const int bA = 4 * tid;           // group A outputs [bA, bA+4)
  const int bB = 1024 + 4 * tid;    // group B outputs [bB, bB+4)
  float acc1A[4], acc1B[4], acc2A[4], acc2B[4];
#pragma unroll
  for (int r = 0; r < 4; ++r) { acc1A[r] = 0.f; acc1B[r] = 0.f; acc2A[r] = 0.f; acc2B[r] = 0.f; }
  if (U0 < U1) {
    // rolling window: a0..a2 cover w[bA+k .. bA+k+12)
    float4 a0 = *(const float4*)&w[bA + U0];
    float4 a1 = *(const float4*)&w[bA + U0 + 4];
    float4 a2 = *(const float4*)&w[bA + U0 + 8];
    float4 b0 = *(const float4*)&w[bB + U0];
    float4 b1 = *(const float4*)&w[bB + U0 + 4];
    float4 b2 = *(const float4*)&w[bB + U0 + 8];
    float4 h1a = *(const float4*)&hs1[U0];
    float4 h1b = *(const float4*)&hs1[U0 + 4];
    float4 h2a = *(const float4*)&hs2[U0];
    float4 h2b = *(const float4*)&hs2[U0 + 4];
    for (int k = U0; k < U1; k += 8) {
      float4 a3 = *(const float4*)&w[bA + k + 12];
      float4 a4 = *(const float4*)&w[bA + k + 16];
      float4 b3 = *(const float4*)&w[bB + k + 12];
      float4 b4 = *(const float4*)&w[bB + k + 16];
      float4 h1an = *(const float4*)&hs1[k + 8];
      float4 h1bn = *(const float4*)&hs1[k + 12];
      float4 h2an = *(const float4*)&hs2[k + 8];
      float4 h2bn = *(const float4*)&hs2[k + 12];
      float wa[11] = {a0.x, a0.y, a0.z, a0.w, a1.x, a1.y, a1.z, a1.w,
                      a2.x, a2.y, a2.z};
      float wb[11] = {b0.x, b0.y, b0.z, b0.w, b1.x, b1.y, b1.z, b1.w,
                      b2.x, b2.y, b2.z};
      float h1[8] = {h1a.x, h1a.y, h1a.z, h1a.w, h1b.x, h1b.y, h1b.z, h1b.w};
      float h2[8] = {h2a.x, h2a.y, h2a.z, h2a.w, h2b.x, h2b.y, h2b.z, h2b.w};
      if (k >= A0 && k < A1) {
#pragma unroll
        for (int r = 0; r < 4; ++r) {
#pragma unroll
          for (int j = 0; j < 8; ++j) {
            acc1A[r] = fmaf(h1[j], wa[r + j], acc1A[r]);
            acc1B[r] = fmaf(h1[j], wb[r + j], acc1B[r]);
          }
        }
      }
      if (k >= B0 && k < B1) {
#pragma unroll
        for (int r = 0; r < 4; ++r) {
#pragma unroll
          for (int j = 0; j < 8; ++j) {
            acc2A[r] = fmaf(h2[j], wa[r + j], acc2A[r]);
            acc2B[r] = fmaf(h2[j], wb[r + j], acc2B[r]);
          }
        }
      }
      a0 = a2; a1 = a3; a2 = a4;
      b0 = b2; b1 = b3; b2 = b4;
      h1a = h1an; h1b = h1bn;
      h2a = h2an; h2b = h2bn;
    }
  }
  // ---- hand off to FFT: z = out1 + i*out2 (overlays dead w/hs region) ----
  __syncthreads();                    // everyone done reading w/hs
#pragma unroll
  for (int r = 0; r < 4; ++r) {
    z[bA + r] = make_float2(acc1A[r], acc2A[r]);
    z[bB + r] = make_float2(acc1B[r], acc2B[r]);
  }
  __syncthreads();
  const float C = 0.70710678118654752f;
  // ---- forward radix-8 DIF stages: Q = 256, 32, 4 ----
#pragma unroll
  for (int st = 0; st < 3; ++st) {
    const int Q = (st == 0) ? 256 : (st == 1) ? 32 : 4;
    const int j = tid & (Q - 1);
    const int base = ((tid & ~(Q - 1)) << 3) + j;
    const float2 x0 = z[base],         x1 = z[base + Q];
    const float2 x2 = z[base + 2 * Q], x3 = z[base + 3 * Q];
    const float2 x4 = z[base + 4 * Q], x5 = z[base + 5 * Q];
    const float2 x6 = z[base + 6 * Q], x7 = z[base + 7 * Q];
    const float2 W1 = tw[4 * Q + j], W2 = tw[2 * Q + j], W4 = tw[Q + j];
    const float2 W3 = cmul(W1, W2);
    const float2 W5 = cmul(W1, W4);
    const float2 W6 = cmul(W2, W4);
    const float2 W7 = cmul(W3, W4);
    const float2 s0 = CADD(x0, x4), s1 = CSUB(x0, x4);
    const float2 s2 = CADD(x2, x6), s3 = CSUB(x2, x6);
    const float2 E0 = CADD(s0, s2), E2 = CSUB(s0, s2);
    const float2 E1 = make_float2(s1.x + s3.y, s1.y - s3.x);  // s1 - i*s3
    const float2 E3 = make_float2(s1.x - s3.y, s1.y + s3.x);  // s1 + i*s3
    const float2 t0 = CADD(x1, x5), t1 = CSUB(x1, x5);
    const float2 t2 = CADD(x3, x7), t3 = CSUB(x3, x7);
    const float2 O0 = CADD(t0, t2), O2 = CSUB(t0, t2);
    const float2 O1 = make_float2(t1.x + t3.y, t1.y - t3.x);  // t1 - i*t3
    const float2 O3 = make_float2(t1.x - t3.y, t1.y + t3.x);  // t1 + i*t3
    const float2 wO1 = make_float2(C * (O1.x + O1.y), C * (O1.y - O1.x));   // w8*O1
    const float2 w3O3 = make_float2(C * (O3.y - O3.x), -C * (O3.x + O3.y)); // w8^3*O3
    const float2 mO2 = make_float2(O2.y, -O2.x);                            // -i*O2
    const float2 y0 = CADD(E0, O0), y4 = CSUB(E0, O0);
    const float2 y1 = CADD(E1, wO1), y5 = CSUB(E1, wO1);
    const float2 y2 = CADD(E2, mO2), y6 = CSUB(E2, mO2);
    const float2 y3 = CADD(E3, w3O3), y7 = CSUB(E3, w3O3);
    z[base]         = y0;
    z[base + Q]     = cmul(y1, W1);
    z[base + 2 * Q] = cmul(y2, W2);
    z[base + 3 * Q] = cmul(y3, W3);
    z[base + 4 * Q] = cmul(y4, W4);
    z[base + 5 * Q] = cmul(y5, W5);
    z[base + 6 * Q] = cmul(y6, W6);
    z[base + 7 * Q] = cmul(y7, W7);
    __syncthreads();
  }
  // ---- forward radix-4 stage (Q=1, twiddles = 1) ----
  for (int bf = tid; bf < 512; bf += 256) {
    const int base = bf << 2;
    const float2 x0 = z[base], x1 = z[base + 1];
    const float2 x2 = z[base + 2], x3 = z[base + 3];
    const float2 t0 = CADD(x0, x2), t1 = CSUB(x0, x2);
    const float2 t2 = CADD(x1, x3), t3 = CSUB(x1, x3);
    z[base]     = CADD(t0, t2);
    z[base + 1] = make_float2(t1.x + t3.y, t1.y - t3.x);  // t1 - i*t3
    z[base + 2] = CSUB(t0, t2);
    z[base + 3] = make_float2(t1.x - t3.y, t1.y + t3.x);  // t1 + i*t3
  }
  __syncthreads();
  // ---- Hilbert mask in digit-reversed space (rule unchanged) ----
  for (int pp = tid; pp < TT; pp += 256) {
    if (pp != 0 && pp != 2) {
      if (pp & 2) { z[pp] = make_float2(0.f, 0.f); }
      else        { float2 v = z[pp]; z[pp] = make_float2(2.f * v.x, 2.f * v.y); }
    }
  }
  __syncthreads();
  // ---- inverse radix-4 stage (Q=1, conj twiddles = 1) ----
  for (int bf = tid; bf < 512; bf += 256) {
    const int base = bf << 2;
    const float2 u0 = z[base], u1 = z[base + 1];
    const float2 u2 = z[base + 2], u3 = z[base + 3];
    const float2 t0 = CADD(u0, u2), t1 = CSUB(u0, u2);
    const float2 t2 = CADD(u1, u3), t3 = CSUB(u1, u3);
    z[base]     = CADD(t0, t2);
    z[base + 1] = make_float2(t1.x - t3.y, t1.y + t3.x);  // t1 + i*t3
    z[base + 2] = CSUB(t0, t2);
    z[base + 3] = make_float2(t1.x + t3.y, t1.y - t3.x);  // t1 - i*t3
  }
  __syncthreads();
  // ---- inverse radix-8 DIT stages: Q = 4, 32, 256 (conj twiddles) ----
#pragma unroll
  for (int st = 0; st < 3; ++st) {
    const int Q = (st == 0) ? 4 : (st == 1) ? 32 : 256;
    const int j = tid & (Q - 1);
    const int base = ((tid & ~(Q - 1)) << 3) + j;
    const float2 W1 = tw[4 * Q + j], W2 = tw[2 * Q + j], W4 = tw[Q + j];
    const float2 W3 = cmul(W1, W2);
    const float2 W5 = cmul(W1, W4);
    const float2 W6 = cmul(W2, W4);
    const float2 W7 = cmul(W3, W4);
    const float2 u0 = z[base];
    const float2 u1 = cmulc(z[base + Q], W1);
    const float2 u2 = cmulc(z[base + 2 * Q], W2);
    const float2 u3 = cmulc(z[base + 3 * Q], W3);
    const float2 u4 = cmulc(z[base + 4 * Q], W4);
    const float2 u5 = cmulc(z[base + 5 * Q], W5);
    const float2 u6 = cmulc(z[base + 6 * Q], W6);
    const float2 u7 = cmulc(z[base + 7 * Q], W7);
    const float2 s0 = CADD(u0, u4), s1 = CSUB(u0, u4);
    const float2 s2 = CADD(u2, u6), s3 = CSUB(u2, u6);
    const float2 E0 = CADD(s0, s2), E2 = CSUB(s0, s2);
    const float2 E1 = make_float2(s1.x - s3.y, s1.y + s3.x);  // s1 + i*s3
    const float2 E3 = make_float2(s1.x + s3.y, s1.y - s3.x);  // s1 - i*s3
    const float2 t0 = CADD(u1, u5), t1 = CSUB(u1, u5);
    const float2 t2 = CADD(u3, u7), t3 = CSUB(u3, u7);
    const float2 O0 = CADD(t0, t2), O2 = CSUB(t0, t2);
    const float2 O1 = make_float2(t1.x - t3.y, t1.y + t3.x);  // t1 + i*t3
    const float2 O3 = make_float2(t1.x + t3.y, t1.y - t3.x);  // t1 - i*t3
    const float2 nO1 = make_float2(C * (O1.x - O1.y), C * (O1.x + O1.y));   // v8*O1
    const float2 n3O3 = make_float2(-C * (O3.x + O3.y), C * (O3.x - O3.y)); // v8^3*O3
    const float2 iO2 = make_float2(-O2.y, O2.x);                            // +i*O2
    z[base]         = CADD(E0, O0);
    z[base + 4 * Q] = CSUB(E0, O0);
    z[base + Q]     = CADD(E1, nO1);
    z[base + 5 * Q] = CSUB(E1, nO1);
    z[base + 2 * Q] = CADD(E2, iO2);
    z[base + 6 * Q] = CSUB(E2, iO2);
    z[base + 3 * Q] = CADD(E3, n3O3);
    z[base + 7 * Q] = CSUB(E3, n3O3);
    __syncthreads();
  }
  // ---- epilogue: phase for o1, amp for o2; x1,x2 still in registers ----
  float* out1 = filt + ((size_t)n * NF + o1) * TT;
  float* out2 = filt + ((size_t)n * NF + o2) * TT;
  const float invN = 1.0f / 2048.0f;
  float phA[4], phB[4], amA[4], amB[4];
#pragma unroll
  for (int r = 0; r < 4; ++r) {
    float2 wvA = z[bA + r];
    float h1 = wvA.y * invN - acc2A[r];
    float h2 = acc1A[r] - wvA.x * invN;
    phA[r] = atan2f(h1, acc1A[r]);
    amA[r] = sqrtf(fmaf(acc2A[r], acc2A[r], h2 * h2));
    float2 wvB = z[bB + r];
    float g1 = wvB.y * invN - acc2B[r];
    float g2 = acc1B[r] - wvB.x * invN;
    phB[r] = atan2f(g1, acc1B[r]);
    amB[r] = sqrtf(fmaf(acc2B[r], acc2B[r], g2 * g2));
  }
  *(float4*)&out1[bA] = make_float4(phA[0], phA[1], phA[2], phA[3]);
  *(float4*)&out1[bB] = make_float4(phB[0], phB[1], phB[2], phB[3]);
  *(float4*)&out2[bA] = make_float4(amA[0], amA[1], amA[2], amA[3]);
  *(float4*)&out2[bB] = make_float4(amB[0], amB[1], amB[2], amB[3]);
}

// ---------------------------------------------------------------------------
// Kernel C: binned MI via MFMA (R16 version: 4 waves/block K-split, fp32
// filt input, in-kernel exact bf16 split; verified 16x16x32 layouts).
// ---------------------------------------------------------------------------
__global__ __launch_bounds__(256) void mi_kernel(const float* __restrict__ filt,
                                                 float* __restrict__ mi) {
  __shared__ __align__(16) unsigned int idx32[512];  // 4 bins/dword
  __shared__ float Cp[4][12][19];                    // per-wave partial C
  const int tid = threadIdx.x;
  const int wave = tid >> 6;
  const int lane = tid & 63;
  const int blk = blockIdx.x;           // bc*40 + jp
  const int bc = blk / 40, jp = blk % 40;
  const float* ph = filt + ((size_t)(bc * 4 + jp / 10) * NF + (jp % 10)) * TT;
  for (int g = tid; g < 512; g += 256) {
    float4 v = *(const float4*)&ph[4 * g];
    float vv[4] = {v.x, v.y, v.z, v.w};
    unsigned int packed = 0;
#pragma unroll
    for (int j = 0; j < 4; ++j) {
      int b = (int)floorf((vv[j] + 3.14159274f) / 6.2831855f * 18.0f);
      b = b < 0 ? 0 : (b > 17 ? 17 : b);
      packed |= ((unsigned int)b) << (8 * j);
    }
    idx32[g] = packed;
  }
  __syncthreads();
  const int n16 = lane & 15;    // A row m / B col n / C col
  const int quad = lane >> 4;   // k-quad (0..3)
  const int aband = n16 < 10 ? n16 : 9;
  const int ja = (jp & 3) + 4 * aband;   // scrambled amp row, same s'
  const float* aptr = filt + ((size_t)(bc * 4 + ja / 10) * NF + 10 + (ja % 10)) * TT
                      + quad * 8;
  const bool isAmp = (n16 < 10);
  const bool isOne = (n16 == 10);
  f32x4 acc0 = {0.f, 0.f, 0.f, 0.f};     // bins 0..15
  f32x4 acc1 = {0.f, 0.f, 0.f, 0.f};     // bins 16..17 (cols 16+n16)
  const int s0 = wave * 16, s1 = s0 + 16;
  float4 p0 = *(const float4*)(aptr + s0 * 32);
  float4 p1 = *(const float4*)(aptr + s0 * 32 + 4);
  for (int s = s0; s < s1; ++s) {
    float4 c0 = p0, c1 = p1;
    if (s < s1 - 1) {
      p0 = *(const float4*)(aptr + (s + 1) * 32);
      p1 = *(const float4*)(aptr + (s + 1) * 32 + 4);
    }
    float a[8] = {c0.x, c0.y, c0.z, c0.w, c1.x, c1.y, c1.z, c1.w};
    short8 ah, am_, al;
#pragma unroll
    for (int j = 0; j < 8; ++j) {
      float v = isAmp ? a[j] : (isOne ? 1.0f : 0.0f);
      unsigned int u = __float_as_uint(v);
      float h = __uint_as_float(u & 0xFFFF0000u);
      float r1 = v - h;                       // exact (<=16 sig bits)
      unsigned int u2 = __float_as_uint(r1);
      float md = __uint_as_float(u2 & 0xFFFF0000u);
      float r2 = r1 - md;                     // exact (<=8 sig bits)
      unsigned int u3 = __float_as_uint(r2);
      ah[j] = (short)(u >> 16);
      am_[j] = (short)(u2 >> 16);
      al[j] = (short)(u3 >> 16);
    }
    const int dw = s * 8 + quad * 2;
    unsigned int d0 = idx32[dw], d1 = idx32[dw + 1];
    short8 b0, b1;
#pragma unroll
    for (int j = 0; j < 8; ++j) {
      unsigned int byte = ((j < 4 ? d0 : d1) >> ((j & 3) * 8)) & 0xFFu;
      b0[j] = (byte == (unsigned int)n16) ? (short)0x3F80 : (short)0;
      b1[j] = (byte == (unsigned int)(n16 + 16)) ? (short)0x3F80 : (short)0;
    }
    acc0 = __builtin_amdgcn_mfma_f32_16x16x32_bf16(ah, b0, acc0, 0, 0, 0);
    acc0 = __builtin_amdgcn_mfma_f32_16x16x32_bf16(am_, b0, acc0, 0, 0, 0);
    acc0 = __builtin_amdgcn_mfma_f32_16x16x32_bf16(al, b0, acc0, 0, 0, 0);
    acc1 = __builtin_amdgcn_mfma_f32_16x16x32_bf16(ah, b1, acc1, 0, 0, 0);
    acc1 = __builtin_amdgcn_mfma_f32_16x16x32_bf16(am_, b1, acc1, 0, 0, 0);
    acc1 = __builtin_amdgcn_mfma_f32_16x16x32_bf16(al, b1, acc1, 0, 0, 0);
  }
#pragma unroll
  for (int r = 0; r < 4; ++r) {
    int row = quad * 4 + r;
    if (row < 11) {
      Cp[wave][row][n16] = acc0[r];
      if (n16 < 2) Cp[wave][row][16 + n16] = acc1[r];
    }
  }
  __syncthreads();
  if (tid < 10) {
    float tot = 0.f, mb_[18];
#pragma unroll
    for (int b = 0; b < 18; ++b) {
      float s = Cp[0][tid][b] + Cp[1][tid][b] + Cp[2][tid][b] + Cp[3][tid][b];
      float c = Cp[0][10][b] + Cp[1][10][b] + Cp[2][10][b] + Cp[3][10][b];
      float mb = s / fmaxf(c, 1.0f);
      mb_[b] = mb; tot += mb;
    }
    tot = fmaxf(tot, 1e-12f);
    float s = 0.f;
#pragma unroll
    for (int b = 0; b < 18; ++b) {
      float pb = mb_[b] / tot;
      s += pb * logf(fmaxf(pb, 1e-12f));
    }
    const float LOGN = 2.8903717578961645f; // log(18)
    mi[(size_t)blk * 10 + tid] = (LOGN + s) / LOGN;
  }
}

// ---------------------------------------------------------------------------
// Kernel D: mean over the scrambled s' axis -> out (4,8,10,10)
// ---------------------------------------------------------------------------
__global__ void out_kernel(const float* __restrict__ mi, float* __restrict__ out) {
  int i = blockIdx.x * 256 + threadIdx.x;
  if (i < 3200) {
    int a = i % 10, p = (i / 10) % 10, bc = i / 100;
    float s = 0.f;
    for (int sp = 0; sp < 4; ++sp)
      s += mi[((size_t)(bc * 40 + p * 4 + sp)) * 10 + a];
    out[i] = 0.25f * s;
  }
}

extern "C" void kernel_launch(void* const* d_in, const int* in_sizes, int n_in,
                              void* d_out, int out_size, void* d_ws, size_t ws_size,
                              hipStream_t stream) {
  (void)in_sizes; (void)n_in; (void)out_size; (void)ws_size;
  const float* x = (const float*)d_in[0];     // (4,8,4,2048) fp32
  const float* ker = (const float*)d_in[1];   // (20,769) fp32
  float* out = (float*)d_out;                 // 3200 fp32
  float* filt = (float*)d_ws;                 // 128*20*2048 fp32 (~21 MB)
  float* mi = filt + (size_t)NS * NF * TT;    // 12800 fp32
  float2* tw = (float2*)(mi + 12800);         // 2048 float2 (16 KB)
  float* hsym = (float*)(tw + TT);            // 20*784 fp32
  int* rng = (int*)(hsym + NF * 784);         // 40 ints

  prep_kernel<<<28, 256, 0, stream>>>(ker, tw, hsym, rng);
  convhil_kernel<<<NS * 10, 256, 0, stream>>>(x, hsym, rng, tw, filt);
  mi_kernel<<<32 * 40, 256, 0, stream>>>(filt, mi);
  out_kernel<<<(3200 + 255) / 256, 256, 0, stream>>>(mi, out);
}

// Round 19
// 129.361 us; speedup vs baseline: 1.0988x; 1.0378x over previous
//
#include <hip/hip_runtime.h>
#include <math.h>

#define TT 2048
#define LK 769
#define NF 20
#define NS 128
#define NB 18

typedef __attribute__((ext_vector_type(8))) short short8;
typedef __attribute__((ext_vector_type(4))) float f32x4;

__device__ __forceinline__ float2 cmul(float2 a, float2 b) {
  return make_float2(a.x * b.x - a.y * b.y, a.x * b.y + a.y * b.x);
}
__device__ __forceinline__ float2 cmulc(float2 a, float2 b) {  // a * conj(b)
  return make_float2(a.x * b.x + a.y * b.y, a.y * b.x - a.x * b.y);
}
#define CADD(a, b) make_float2((a).x + (b).x, (a).y + (b).y)
#define CSUB(a, b) make_float2((a).x - (b).x, (a).y - (b).y)

// ---------------------------------------------------------------------------
// Kernel P: one-time prep (unchanged): twiddles + symmetrized filters +
// 8-aligned nonzero ranges.
// ---------------------------------------------------------------------------
__global__ __launch_bounds__(256) void prep_kernel(const float* __restrict__ ker,
                                                   float2* __restrict__ tw,
                                                   float* __restrict__ hsym,
                                                   int* __restrict__ rng) {
  __shared__ int red[4][2];
  const int blk = blockIdx.x;
  const int tid = threadIdx.x;
  if (blk < 8) {
    int i = blk * 256 + tid;
    if (i == 0) { tw[0] = make_float2(1.f, 0.f); }
    else {
      int half = 1 << (31 - __clz(i));
      int j = i - half;
      float ang = -3.14159265358979323846f * (float)j / (float)half;
      float s, c;
      sincosf(ang, &s, &c);
      tw[i] = make_float2(c, s);
    }
    return;
  }
  const int o = blk - 8;
  const float* kr = ker + o * LK;
  int k0 = 784, k1 = 0;
  for (int k = tid; k < 784; k += 256) {
    float v = 0.f;
    if (k < LK) v = 0.5f * (kr[k] + kr[LK - 1 - k]);
    hsym[o * 784 + k] = v;
    if (v != 0.f) { k0 = min(k0, k); k1 = max(k1, k + 1); }
  }
#pragma unroll
  for (int off = 32; off > 0; off >>= 1) {
    k0 = min(k0, __shfl_down(k0, off));
    k1 = max(k1, __shfl_down(k1, off));
  }
  if ((tid & 63) == 0) { red[tid >> 6][0] = k0; red[tid >> 6][1] = k1; }
  __syncthreads();
  if (tid == 0) {
    k0 = min(min(red[0][0], red[1][0]), min(red[2][0], red[3][0]));
    k1 = max(max(red[0][1], red[1][1]), max(red[2][1], red[3][1]));
    rng[2 * o] = k0 & ~7;              // 8-aligned (extra taps exact zeros)
    rng[2 * o + 1] = (k1 + 7) & ~7;
  }
}

// ---------------------------------------------------------------------------
// Kernel A: FUSED conv + Hilbert (R18 structure, 8*8*8*4 FFT). R19: taps
// read directly from global hsym with WAVE-UNIFORM addresses -> compiler
// emits s_load (scalar pipe, values in SGPRs). Removes 4 of the 8
// ds_read_b128 per conv iteration and the hs LDS staging pass (6.3 KB).
// Tap values bit-identical (same prep output) -> conv arithmetic bit-exact.
// ---------------------------------------------------------------------------
__global__ __launch_bounds__(256) void convhil_kernel(const float* __restrict__ x,
                                                      const float* __restrict__ hsym,
                                                      const int* __restrict__ rng,
                                                      const float2* __restrict__ tw,
                                                      float* __restrict__ filt) {
  __shared__ __align__(16) float smem[4096];   // w[2832]; z (4096 floats) overlays
  float* w   = smem;
  float2* z  = (float2*)smem;                  // 2048 float2
  const int tid = threadIdx.x;
  const int ord = blockIdx.x;
  const int p = ord / NS;                   // 0..9, longest pair first
  const int n = ord % NS;
  const int o1 = p;                          // pha band
  const int o2 = 10 + (9 - p);               // amp band (short with long)
  const float* xr = x + n * TT;
  for (int j = tid; j < 2832; j += 256) {
    float v = 0.f;
    if (j < 2816) {
      int m = j - 384;              // spad[j+384] -> original index (j+384)-768
      if (m < 0) m = -m;            // reflect (edge excluded)
      if (m > 2047) m = 4094 - m;
      v = xr[m];
    }
    w[j] = v;
  }
  const float* h1g = hsym + o1 * 784;        // uniform base -> scalar loads
  const float* h2g = hsym + o2 * 784;
  const int A0 = rng[2 * o1], A1 = rng[2 * o1 + 1];   // uniform -> scalar loads
  const int B0 = rng[2 * o2], B1 = rng[2 * o2 + 1];
  const int U0 = min(A0, B0);
  const int U1 = max(A1, B1);
  __syncthreads();

  const int bA = 4 * tid;           // group A outputs [bA, bA+4)
  const int bB = 1024 + 4 * tid;    // group B outputs [bB, bB+4)
  float acc1A[4], acc1B[4], acc2A[4], acc2B[4];
#pragma unroll
  for (int r = 0; r < 4; ++r) { acc1A[r] = 0.f; acc1B[r] = 0.f; acc2A[r] = 0.f; acc2B[r] = 0.f; }
  if (U0 < U1) {
    // rolling window: a0..a2 cover w[bA+k .. bA+k+12)
    float4 a0 = *(const float4*)&w[bA + U0];
    float4 a1 = *(const float4*)&w[bA + U0 + 4];
    float4 a2 = *(const float4*)&w[bA + U0 + 8];
    float4 b0 = *(const float4*)&w[bB + U0];
    float4 b1 = *(const float4*)&w[bB + U0 + 4];
    float4 b2 = *(const float4*)&w[bB + U0 + 8];
    float4 h1a = *(const float4*)&h1g[U0];     // uniform -> s_load_dwordx4
    float4 h1b = *(const float4*)&h1g[U0 + 4];
    float4 h2a = *(const float4*)&h2g[U0];
    float4 h2b = *(const float4*)&h2g[U0 + 4];
    for (int k = U0; k < U1; k += 8) {
      float4 a3 = *(const float4*)&w[bA + k + 12];
      float4 a4 = *(const float4*)&w[bA + k + 16];
      float4 b3 = *(const float4*)&w[bB + k + 12];
      float4 b4 = *(const float4*)&w[bB + k + 16];
      float4 h1an = *(const float4*)&h1g[k + 8];    // scalar prefetch
      float4 h1bn = *(const float4*)&h1g[k + 12];
      float4 h2an = *(const float4*)&h2g[k + 8];
      float4 h2bn = *(const float4*)&h2g[k + 12];
      float wa[11] = {a0.x, a0.y, a0.z, a0.w, a1.x, a1.y, a1.z, a1.w,
                      a2.x, a2.y, a2.z};
      float wb[11] = {b0.x, b0.y, b0.z, b0.w, b1.x, b1.y, b1.z, b1.w,
                      b2.x, b2.y, b2.z};
      float h1[8] = {h1a.x, h1a.y, h1a.z, h1a.w, h1b.x, h1b.y, h1b.z, h1b.w};
      float h2[8] = {h2a.x, h2a.y, h2a.z, h2a.w, h2b.x, h2b.y, h2b.z, h2b.w};
      if (k >= A0 && k < A1) {
#pragma unroll
        for (int r = 0; r < 4; ++r) {
#pragma unroll
          for (int j = 0; j < 8; ++j) {
            acc1A[r] = fmaf(h1[j], wa[r + j], acc1A[r]);
            acc1B[r] = fmaf(h1[j], wb[r + j], acc1B[r]);
          }
        }
      }
      if (k >= B0 && k < B1) {
#pragma unroll
        for (int r = 0; r < 4; ++r) {
#pragma unroll
          for (int j = 0; j < 8; ++j) {
            acc2A[r] = fmaf(h2[j], wa[r + j], acc2A[r]);
            acc2B[r] = fmaf(h2[j], wb[r + j], acc2B[r]);
          }
        }
      }
      a0 = a2; a1 = a3; a2 = a4;
      b0 = b2; b1 = b3; b2 = b4;
      h1a = h1an; h1b = h1bn;
      h2a = h2an; h2b = h2bn;
    }
  }
  // ---- hand off to FFT: z = out1 + i*out2 (overlays dead w region) ----
  __syncthreads();                    // everyone done reading w
#pragma unroll
  for (int r = 0; r < 4; ++r) {
    z[bA + r] = make_float2(acc1A[r], acc2A[r]);
    z[bB + r] = make_float2(acc1B[r], acc2B[r]);
  }
  __syncthreads();
  const float C = 0.70710678118654752f;
  // ---- forward radix-8 DIF stages: Q = 256, 32, 4 ----
#pragma unroll
  for (int st = 0; st < 3; ++st) {
    const int Q = (st == 0) ? 256 : (st == 1) ? 32 : 4;
    const int j = tid & (Q - 1);
    const int base = ((tid & ~(Q - 1)) << 3) + j;
    const float2 x0 = z[base],         x1 = z[base + Q];
    const float2 x2 = z[base + 2 * Q], x3 = z[base + 3 * Q];
    const float2 x4 = z[base + 4 * Q], x5 = z[base + 5 * Q];
    const float2 x6 = z[base + 6 * Q], x7 = z[base + 7 * Q];
    const float2 W1 = tw[4 * Q + j], W2 = tw[2 * Q + j], W4 = tw[Q + j];
    const float2 W3 = cmul(W1, W2);
    const float2 W5 = cmul(W1, W4);
    const float2 W6 = cmul(W2, W4);
    const float2 W7 = cmul(W3, W4);
    const float2 s0 = CADD(x0, x4), s1 = CSUB(x0, x4);
    const float2 s2 = CADD(x2, x6), s3 = CSUB(x2, x6);
    const float2 E0 = CADD(s0, s2), E2 = CSUB(s0, s2);
    const float2 E1 = make_float2(s1.x + s3.y, s1.y - s3.x);  // s1 - i*s3
    const float2 E3 = make_float2(s1.x - s3.y, s1.y + s3.x);  // s1 + i*s3
    const float2 t0 = CADD(x1, x5), t1 = CSUB(x1, x5);
    const float2 t2 = CADD(x3, x7), t3 = CSUB(x3, x7);
    const float2 O0 = CADD(t0, t2), O2 = CSUB(t0, t2);
    const float2 O1 = make_float2(t1.x + t3.y, t1.y - t3.x);  // t1 - i*t3
    const float2 O3 = make_float2(t1.x - t3.y, t1.y + t3.x);  // t1 + i*t3
    const float2 wO1 = make_float2(C * (O1.x + O1.y), C * (O1.y - O1.x));   // w8*O1
    const float2 w3O3 = make_float2(C * (O3.y - O3.x), -C * (O3.x + O3.y)); // w8^3*O3
    const float2 mO2 = make_float2(O2.y, -O2.x);                            // -i*O2
    const float2 y0 = CADD(E0, O0), y4 = CSUB(E0, O0);
    const float2 y1 = CADD(E1, wO1), y5 = CSUB(E1, wO1);
    const float2 y2 = CADD(E2, mO2), y6 = CSUB(E2, mO2);
    const float2 y3 = CADD(E3, w3O3), y7 = CSUB(E3, w3O3);
    z[base]         = y0;
    z[base + Q]     = cmul(y1, W1);
    z[base + 2 * Q] = cmul(y2, W2);
    z[base + 3 * Q] = cmul(y3, W3);
    z[base + 4 * Q] = cmul(y4, W4);
    z[base + 5 * Q] = cmul(y5, W5);
    z[base + 6 * Q] = cmul(y6, W6);
    z[base + 7 * Q] = cmul(y7, W7);
    __syncthreads();
  }
  // ---- forward radix-4 stage (Q=1, twiddles = 1) ----
  for (int bf = tid; bf < 512; bf += 256) {
    const int base = bf << 2;
    const float2 x0 = z[base], x1 = z[base + 1];
    const float2 x2 = z[base + 2], x3 = z[base + 3];
    const float2 t0 = CADD(x0, x2), t1 = CSUB(x0, x2);
    const float2 t2 = CADD(x1, x3), t3 = CSUB(x1, x3);
    z[base]     = CADD(t0, t2);
    z[base + 1] = make_float2(t1.x + t3.y, t1.y - t3.x);  // t1 - i*t3
    z[base + 2] = CSUB(t0, t2);
    z[base + 3] = make_float2(t1.x - t3.y, t1.y + t3.x);  // t1 + i*t3
  }
  __syncthreads();
  // ---- Hilbert mask in digit-reversed space (rule unchanged) ----
  for (int pp = tid; pp < TT; pp += 256) {
    if (pp != 0 && pp != 2) {
      if (pp & 2) { z[pp] = make_float2(0.f, 0.f); }
      else        { float2 v = z[pp]; z[pp] = make_float2(2.f * v.x, 2.f * v.y); }
    }
  }
  __syncthreads();
  // ---- inverse radix-4 stage (Q=1, conj twiddles = 1) ----
  for (int bf = tid; bf < 512; bf += 256) {
    const int base = bf << 2;
    const float2 u0 = z[base], u1 = z[base + 1];
    const float2 u2 = z[base + 2], u3 = z[base + 3];
    const float2 t0 = CADD(u0, u2), t1 = CSUB(u0, u2);
    const float2 t2 = CADD(u1, u3), t3 = CSUB(u1, u3);
    z[base]     = CADD(t0, t2);
    z[base + 1] = make_float2(t1.x - t3.y, t1.y + t3.x);  // t1 + i*t3
    z[base + 2] = CSUB(t0, t2);
    z[base + 3] = make_float2(t1.x + t3.y, t1.y - t3.x);  // t1 - i*t3
  }
  __syncthreads();
  // ---- inverse radix-8 DIT stages: Q = 4, 32, 256 (conj twiddles) ----
#pragma unroll
  for (int st = 0; st < 3; ++st) {
    const int Q = (st == 0) ? 4 : (st == 1) ? 32 : 256;
    const int j = tid & (Q - 1);
    const int base = ((tid & ~(Q - 1)) << 3) + j;
    const float2 W1 = tw[4 * Q + j], W2 = tw[2 * Q + j], W4 = tw[Q + j];
    const float2 W3 = cmul(W1, W2);
    const float2 W5 = cmul(W1, W4);
    const float2 W6 = cmul(W2, W4);
    const float2 W7 = cmul(W3, W4);
    const float2 u0 = z[base];
    const float2 u1 = cmulc(z[base + Q], W1);
    const float2 u2 = cmulc(z[base + 2 * Q], W2);
    const float2 u3 = cmulc(z[base + 3 * Q], W3);
    const float2 u4 = cmulc(z[base + 4 * Q], W4);
    const float2 u5 = cmulc(z[base + 5 * Q], W5);
    const float2 u6 = cmulc(z[base + 6 * Q], W6);
    const float2 u7 = cmulc(z[base + 7 * Q], W7);
    const float2 s0 = CADD(u0, u4), s1 = CSUB(u0, u4);
    const float2 s2 = CADD(u2, u6), s3 = CSUB(u2, u6);
    const float2 E0 = CADD(s0, s2), E2 = CSUB(s0, s2);
    const float2 E1 = make_float2(s1.x - s3.y, s1.y + s3.x);  // s1 + i*s3
    const float2 E3 = make_float2(s1.x + s3.y, s1.y - s3.x);  // s1 - i*s3
    const float2 t0 = CADD(u1, u5), t1 = CSUB(u1, u5);
    const float2 t2 = CADD(u3, u7), t3 = CSUB(u3, u7);
    const float2 O0 = CADD(t0, t2), O2 = CSUB(t0, t2);
    const float2 O1 = make_float2(t1.x - t3.y, t1.y + t3.x);  // t1 + i*t3
    const float2 O3 = make_float2(t1.x + t3.y, t1.y - t3.x);  // t1 - i*t3
    const float2 nO1 = make_float2(C * (O1.x - O1.y), C * (O1.x + O1.y));   // v8*O1
    const float2 n3O3 = make_float2(-C * (O3.x + O3.y), C * (O3.x - O3.y)); // v8^3*O3
    const float2 iO2 = make_float2(-O2.y, O2.x);                            // +i*O2
    z[base]         = CADD(E0, O0);
    z[base + 4 * Q] = CSUB(E0, O0);
    z[base + Q]     = CADD(E1, nO1);
    z[base + 5 * Q] = CSUB(E1, nO1);
    z[base + 2 * Q] = CADD(E2, iO2);
    z[base + 6 * Q] = CSUB(E2, iO2);
    z[base + 3 * Q] = CADD(E3, n3O3);
    z[base + 7 * Q] = CSUB(E3, n3O3);
    __syncthreads();
  }
  // ---- epilogue: phase for o1, amp for o2; x1,x2 still in registers ----
  float* out1 = filt + ((size_t)n * NF + o1) * TT;
  float* out2 = filt + ((size_t)n * NF + o2) * TT;
  const float invN = 1.0f / 2048.0f;
  float phA[4], phB[4], amA[4], amB[4];
#pragma unroll
  for (int r = 0; r < 4; ++r) {
    float2 wvA = z[bA + r];
    float h1 = wvA.y * invN - acc2A[r];
    float h2 = acc1A[r] - wvA.x * invN;
    phA[r] = atan2f(h1, acc1A[r]);
    amA[r] = sqrtf(fmaf(acc2A[r], acc2A[r], h2 * h2));
    float2 wvB = z[bB + r];
    float g1 = wvB.y * invN - acc2B[r];
    float g2 = acc1B[r] - wvB.x * invN;
    phB[r] = atan2f(g1, acc1B[r]);
    amB[r] = sqrtf(fmaf(acc2B[r], acc2B[r], g2 * g2));
  }
  *(float4*)&out1[bA] = make_float4(phA[0], phA[1], phA[2], phA[3]);
  *(float4*)&out1[bB] = make_float4(phB[0], phB[1], phB[2], phB[3]);
  *(float4*)&out2[bA] = make_float4(amA[0], amA[1], amA[2], amA[3]);
  *(float4*)&out2[bB] = make_float4(amB[0], amB[1], amB[2], amB[3]);
}

// ---------------------------------------------------------------------------
// Kernel C: binned MI via MFMA (unchanged: 4 waves/block K-split, verified
// 16x16x32 layouts, 3-way exact bf16 split, counts via ones-row).
// ---------------------------------------------------------------------------
__global__ __launch_bounds__(256) void mi_kernel(const float* __restrict__ filt,
                                                 float* __restrict__ mi) {
  __shared__ __align__(16) unsigned int idx32[512];  // 4 bins/dword
  __shared__ float Cp[4][12][19];                    // per-wave partial C
  const int tid = threadIdx.x;
  const int wave = tid >> 6;
  const int lane = tid & 63;
  const int blk = blockIdx.x;           // bc*40 + jp
  const int bc = blk / 40, jp = blk % 40;
  const float* ph = filt + ((size_t)(bc * 4 + jp / 10) * NF + (jp % 10)) * TT;
  for (int g = tid; g < 512; g += 256) {
    float4 v = *(const float4*)&ph[4 * g];
    float vv[4] = {v.x, v.y, v.z, v.w};
    unsigned int packed = 0;
#pragma unroll
    for (int j = 0; j < 4; ++j) {
      int b = (int)floorf((vv[j] + 3.14159274f) / 6.2831855f * 18.0f);
      b = b < 0 ? 0 : (b > 17 ? 17 : b);
      packed |= ((unsigned int)b) << (8 * j);
    }
    idx32[g] = packed;
  }
  __syncthreads();
  const int n16 = lane & 15;    // A row m / B col n / C col
  const int quad = lane >> 4;   // k-quad (0..3)
  const int aband = n16 < 10 ? n16 : 9;
  const int ja = (jp & 3) + 4 * aband;   // scrambled amp row, same s'
  const float* aptr = filt + ((size_t)(bc * 4 + ja / 10) * NF + 10 + (ja % 10)) * TT
                      + quad * 8;
  const bool isAmp = (n16 < 10);
  const bool isOne = (n16 == 10);
  f32x4 acc0 = {0.f, 0.f, 0.f, 0.f};     // bins 0..15
  f32x4 acc1 = {0.f, 0.f, 0.f, 0.f};     // bins 16..17 (cols 16+n16)
  const int s0 = wave * 16, s1 = s0 + 16;
  float4 p0 = *(const float4*)(aptr + s0 * 32);
  float4 p1 = *(const float4*)(aptr + s0 * 32 + 4);
  for (int s = s0; s < s1; ++s) {
    float4 c0 = p0, c1 = p1;
    if (s < s1 - 1) {
      p0 = *(const float4*)(aptr + (s + 1) * 32);
      p1 = *(const float4*)(aptr + (s + 1) * 32 + 4);
    }
    float a[8] = {c0.x, c0.y, c0.z, c0.w, c1.x, c1.y, c1.z, c1.w};
    short8 ah, am_, al;
#pragma unroll
    for (int j = 0; j < 8; ++j) {
      float v = isAmp ? a[j] : (isOne ? 1.0f : 0.0f);
      unsigned int u = __float_as_uint(v);
      float h = __uint_as_float(u & 0xFFFF0000u);
      float r1 = v - h;                       // exact (<=16 sig bits)
      unsigned int u2 = __float_as_uint(r1);
      float md = __uint_as_float(u2 & 0xFFFF0000u);
      float r2 = r1 - md;                     // exact (<=8 sig bits)
      unsigned int u3 = __float_as_uint(r2);
      ah[j] = (short)(u >> 16);
      am_[j] = (short)(u2 >> 16);
      al[j] = (short)(u3 >> 16);
    }
    const int dw = s * 8 + quad * 2;
    unsigned int d0 = idx32[dw], d1 = idx32[dw + 1];
    short8 b0, b1;
#pragma unroll
    for (int j = 0; j < 8; ++j) {
      unsigned int byte = ((j < 4 ? d0 : d1) >> ((j & 3) * 8)) & 0xFFu;
      b0[j] = (byte == (unsigned int)n16) ? (short)0x3F80 : (short)0;
      b1[j] = (byte == (unsigned int)(n16 + 16)) ? (short)0x3F80 : (short)0;
    }
    acc0 = __builtin_amdgcn_mfma_f32_16x16x32_bf16(ah, b0, acc0, 0, 0, 0);
    acc0 = __builtin_amdgcn_mfma_f32_16x16x32_bf16(am_, b0, acc0, 0, 0, 0);
    acc0 = __builtin_amdgcn_mfma_f32_16x16x32_bf16(al, b0, acc0, 0, 0, 0);
    acc1 = __builtin_amdgcn_mfma_f32_16x16x32_bf16(ah, b1, acc1, 0, 0, 0);
    acc1 = __builtin_amdgcn_mfma_f32_16x16x32_bf16(am_, b1, acc1, 0, 0, 0);
    acc1 = __builtin_amdgcn_mfma_f32_16x16x32_bf16(al, b1, acc1, 0, 0, 0);
  }
#pragma unroll
  for (int r = 0; r < 4; ++r) {
    int row = quad * 4 + r;
    if (row < 11) {
      Cp[wave][row][n16] = acc0[r];
      if (n16 < 2) Cp[wave][row][16 + n16] = acc1[r];
    }
  }
  __syncthreads();
  if (tid < 10) {
    float tot = 0.f, mb_[18];
#pragma unroll
    for (int b = 0; b < 18; ++b) {
      float s = Cp[0][tid][b] + Cp[1][tid][b] + Cp[2][tid][b] + Cp[3][tid][b];
      float c = Cp[0][10][b] + Cp[1][10][b] + Cp[2][10][b] + Cp[3][10][b];
      float mb = s / fmaxf(c, 1.0f);
      mb_[b] = mb; tot += mb;
    }
    tot = fmaxf(tot, 1e-12f);
    float s = 0.f;
#pragma unroll
    for (int b = 0; b < 18; ++b) {
      float pb = mb_[b] / tot;
      s += pb * logf(fmaxf(pb, 1e-12f));
    }
    const float LOGN = 2.8903717578961645f; // log(18)
    mi[(size_t)blk * 10 + tid] = (LOGN + s) / LOGN;
  }
}

// ---------------------------------------------------------------------------
// Kernel D: mean over the scrambled s' axis -> out (4,8,10,10)
// ---------------------------------------------------------------------------
__global__ void out_kernel(const float* __restrict__ mi, float* __restrict__ out) {
  int i = blockIdx.x * 256 + threadIdx.x;
  if (i < 3200) {
    int a = i % 10, p = (i / 10) % 10, bc = i / 100;
    float s = 0.f;
    for (int sp = 0; sp < 4; ++sp)
      s += mi[((size_t)(bc * 40 + p * 4 + sp)) * 10 + a];
    out[i] = 0.25f * s;
  }
}

extern "C" void kernel_launch(void* const* d_in, const int* in_sizes, int n_in,
                              void* d_out, int out_size, void* d_ws, size_t ws_size,
                              hipStream_t stream) {
  (void)in_sizes; (void)n_in; (void)out_size; (void)ws_size;
  const float* x = (const float*)d_in[0];     // (4,8,4,2048) fp32
  const float* ker = (const float*)d_in[1];   // (20,769) fp32
  float* out = (float*)d_out;                 // 3200 fp32
  float* filt = (float*)d_ws;                 // 128*20*2048 fp32 (~21 MB)
  float* mi = filt + (size_t)NS * NF * TT;    // 12800 fp32
  float2* tw = (float2*)(mi + 12800);         // 2048 float2 (16 KB)
  float* hsym = (float*)(tw + TT);            // 20*784 fp32
  int* rng = (int*)(hsym + NF * 784);         // 40 ints

  prep_kernel<<<28, 256, 0, stream>>>(ker, tw, hsym, rng);
  convhil_kernel<<<NS * 10, 256, 0, stream>>>(x, hsym, rng, tw, filt);
  mi_kernel<<<32 * 40, 256, 0, stream>>>(filt, mi);
  out_kernel<<<(3200 + 255) / 256, 256, 0, stream>>>(mi, out);
}

// Round 20
// 128.773 us; speedup vs baseline: 1.1038x; 1.0046x over previous
//
#include <hip/hip_runtime.h>
#include <math.h>

#define TT 2048
#define LK 769
#define NF 20
#define NS 128
#define NB 18

typedef __attribute__((ext_vector_type(8))) short short8;
typedef __attribute__((ext_vector_type(4))) float f32x4;

__device__ __forceinline__ float2 cmul(float2 a, float2 b) {
  return make_float2(a.x * b.x - a.y * b.y, a.x * b.y + a.y * b.x);
}
__device__ __forceinline__ float2 cmulc(float2 a, float2 b) {  // a * conj(b)
  return make_float2(a.x * b.x + a.y * b.y, a.y * b.x - a.x * b.y);
}
#define CADD(a, b) make_float2((a).x + (b).x, (a).y + (b).y)
#define CSUB(a, b) make_float2((a).x - (b).x, (a).y - (b).y)

// ---------------------------------------------------------------------------
// Kernel P: one-time prep (unchanged): twiddles + symmetrized filters +
// 8-aligned nonzero ranges.
// ---------------------------------------------------------------------------
__global__ __launch_bounds__(256) void prep_kernel(const float* __restrict__ ker,
                                                   float2* __restrict__ tw,
                                                   float* __restrict__ hsym,
                                                   int* __restrict__ rng) {
  __shared__ int red[4][2];
  const int blk = blockIdx.x;
  const int tid = threadIdx.x;
  if (blk < 8) {
    int i = blk * 256 + tid;
    if (i == 0) { tw[0] = make_float2(1.f, 0.f); }
    else {
      int half = 1 << (31 - __clz(i));
      int j = i - half;
      float ang = -3.14159265358979323846f * (float)j / (float)half;
      float s, c;
      sincosf(ang, &s, &c);
      tw[i] = make_float2(c, s);
    }
    return;
  }
  const int o = blk - 8;
  const float* kr = ker + o * LK;
  int k0 = 784, k1 = 0;
  for (int k = tid; k < 784; k += 256) {
    float v = 0.f;
    if (k < LK) v = 0.5f * (kr[k] + kr[LK - 1 - k]);
    hsym[o * 784 + k] = v;
    if (v != 0.f) { k0 = min(k0, k); k1 = max(k1, k + 1); }
  }
#pragma unroll
  for (int off = 32; off > 0; off >>= 1) {
    k0 = min(k0, __shfl_down(k0, off));
    k1 = max(k1, __shfl_down(k1, off));
  }
  if ((tid & 63) == 0) { red[tid >> 6][0] = k0; red[tid >> 6][1] = k1; }
  __syncthreads();
  if (tid == 0) {
    k0 = min(min(red[0][0], red[1][0]), min(red[2][0], red[3][0]));
    k1 = max(max(red[0][1], red[1][1]), max(red[2][1], red[3][1]));
    rng[2 * o] = k0 & ~7;              // 8-aligned (extra taps exact zeros)
    rng[2 * o + 1] = (k1 + 7) & ~7;
  }
}

// ---------------------------------------------------------------------------
// Kernel A: FUSED conv + Hilbert (R19 structure: scalar taps, 8*8*8*4 FFT).
// R20: WAVE-SYNCHRONOUS FFT. With bf=tid, wave w's Q=32 and Q=4 radix-8
// stages (and re-indexed Q=1 radix-4 + mask) touch exactly elements
// [512w, 512w+512) — written by the same wave in the prior stage. CDNA DS
// executes a wave's LDS ops in order, so those stage boundaries need only
// __builtin_amdgcn_wave_barrier() (compiler fence, 0 cycles). Full
// __syncthreads() kept only around the Q=256 stages and handoff/epilogue:
// 11 -> 6 barriers. Arithmetic bit-identical to R19.
// ---------------------------------------------------------------------------
__global__ __launch_bounds__(256) void convhil_kernel(const float* __restrict__ x,
                                                      const float* __restrict__ hsym,
                                                      const int* __restrict__ rng,
                                                      const float2* __restrict__ tw,
                                                      float* __restrict__ filt) {
  __shared__ __align__(16) float smem[4096];   // w[2832]; z (4096 floats) overlays
  float* w   = smem;
  float2* z  = (float2*)smem;                  // 2048 float2
  const int tid = threadIdx.x;
  const int wv = tid >> 6;                     // wave id (0..3)
  const int lane = tid & 63;
  const int ord = blockIdx.x;
  const int p = ord / NS;                   // 0..9, longest pair first
  const int n = ord % NS;
  const int o1 = p;                          // pha band
  const int o2 = 10 + (9 - p);               // amp band (short with long)
  const float* xr = x + n * TT;
  for (int j = tid; j < 2832; j += 256) {
    float v = 0.f;
    if (j < 2816) {
      int m = j - 384;              // spad[j+384] -> original index (j+384)-768
      if (m < 0) m = -m;            // reflect (edge excluded)
      if (m > 2047) m = 4094 - m;
      v = xr[m];
    }
    w[j] = v;
  }
  const float* h1g = hsym + o1 * 784;        // uniform base -> scalar loads
  const float* h2g = hsym + o2 * 784;
  const int A0 = rng[2 * o1], A1 = rng[2 * o1 + 1];   // uniform -> scalar loads
  const int B0 = rng[2 * o2], B1 = rng[2 * o2 + 1];
  const int U0 = min(A0, B0);
  const int U1 = max(A1, B1);
  __syncthreads();                                    // barrier 1

  const int bA = 4 * tid;           // group A outputs [bA, bA+4)
  const int bB = 1024 + 4 * tid;    // group B outputs [bB, bB+4)
  float acc1A[4], acc1B[4], acc2A[4], acc2B[4];
#pragma unroll
  for (int r = 0; r < 4; ++r) { acc1A[r] = 0.f; acc1B[r] = 0.f; acc2A[r] = 0.f; acc2B[r] = 0.f; }
  if (U0 < U1) {
    // rolling window: a0..a2 cover w[bA+k .. bA+k+12)
    float4 a0 = *(const float4*)&w[bA + U0];
    float4 a1 = *(const float4*)&w[bA + U0 + 4];
    float4 a2 = *(const float4*)&w[bA + U0 + 8];
    float4 b0 = *(const float4*)&w[bB + U0];
    float4 b1 = *(const float4*)&w[bB + U0 + 4];
    float4 b2 = *(const float4*)&w[bB + U0 + 8];
    float4 h1a = *(const float4*)&h1g[U0];     // uniform -> s_load_dwordx4
    float4 h1b = *(const float4*)&h1g[U0 + 4];
    float4 h2a = *(const float4*)&h2g[U0];
    float4 h2b = *(const float4*)&h2g[U0 + 4];
    for (int k = U0; k < U1; k += 8) {
      float4 a3 = *(const float4*)&w[bA + k + 12];
      float4 a4 = *(const float4*)&w[bA + k + 16];
      float4 b3 = *(const float4*)&w[bB + k + 12];
      float4 b4 = *(const float4*)&w[bB + k + 16];
      float4 h1an = *(const float4*)&h1g[k + 8];    // scalar prefetch
      float4 h1bn = *(const float4*)&h1g[k + 12];
      float4 h2an = *(const float4*)&h2g[k + 8];
      float4 h2bn = *(const float4*)&h2g[k + 12];
      float wa[11] = {a0.x, a0.y, a0.z, a0.w, a1.x, a1.y, a1.z, a1.w,
                      a2.x, a2.y, a2.z};
      float wb[11] = {b0.x, b0.y, b0.z, b0.w, b1.x, b1.y, b1.z, b1.w,
                      b2.x, b2.y, b2.z};
      float h1[8] = {h1a.x, h1a.y, h1a.z, h1a.w, h1b.x, h1b.y, h1b.z, h1b.w};
      float h2[8] = {h2a.x, h2a.y, h2a.z, h2a.w, h2b.x, h2b.y, h2b.z, h2b.w};
      if (k >= A0 && k < A1) {
#pragma unroll
        for (int r = 0; r < 4; ++r) {
#pragma unroll
          for (int j = 0; j < 8; ++j) {
            acc1A[r] = fmaf(h1[j], wa[r + j], acc1A[r]);
            acc1B[r] = fmaf(h1[j], wb[r + j], acc1B[r]);
          }
        }
      }
      if (k >= B0 && k < B1) {
#pragma unroll
        for (int r = 0; r < 4; ++r) {
#pragma unroll
          for (int j = 0; j < 8; ++j) {
            acc2A[r] = fmaf(h2[j], wa[r + j], acc2A[r]);
            acc2B[r] = fmaf(h2[j], wb[r + j], acc2B[r]);
          }
        }
      }
      a0 = a2; a1 = a3; a2 = a4;
      b0 = b2; b1 = b3; b2 = b4;
      h1a = h1an; h1b = h1bn;
      h2a = h2an; h2b = h2bn;
    }
  }
  // ---- hand off to FFT: z = out1 + i*out2 (overlays dead w region) ----
  __syncthreads();                                    // barrier 2
#pragma unroll
  for (int r = 0; r < 4; ++r) {
    z[bA + r] = make_float2(acc1A[r], acc2A[r]);
    z[bB + r] = make_float2(acc1B[r], acc2B[r]);
  }
  __syncthreads();                                    // barrier 3
  const float C = 0.70710678118654752f;
  // ---- forward radix-8 stage Q=256 (cross-wave) ----
  {
    const int Q = 256;
    const int j = tid & (Q - 1);
    const int base = ((tid & ~(Q - 1)) << 3) + j;
    const float2 x0 = z[base],         x1 = z[base + Q];
    const float2 x2 = z[base + 2 * Q], x3 = z[base + 3 * Q];
    const float2 x4 = z[base + 4 * Q], x5 = z[base + 5 * Q];
    const float2 x6 = z[base + 6 * Q], x7 = z[base + 7 * Q];
    const float2 W1 = tw[4 * Q + j], W2 = tw[2 * Q + j], W4 = tw[Q + j];
    const float2 W3 = cmul(W1, W2);
    const float2 W5 = cmul(W1, W4);
    const float2 W6 = cmul(W2, W4);
    const float2 W7 = cmul(W3, W4);
    const float2 s0 = CADD(x0, x4), s1 = CSUB(x0, x4);
    const float2 s2 = CADD(x2, x6), s3 = CSUB(x2, x6);
    const float2 E0 = CADD(s0, s2), E2 = CSUB(s0, s2);
    const float2 E1 = make_float2(s1.x + s3.y, s1.y - s3.x);
    const float2 E3 = make_float2(s1.x - s3.y, s1.y + s3.x);
    const float2 t0 = CADD(x1, x5), t1 = CSUB(x1, x5);
    const float2 t2 = CADD(x3, x7), t3 = CSUB(x3, x7);
    const float2 O0 = CADD(t0, t2), O2 = CSUB(t0, t2);
    const float2 O1 = make_float2(t1.x + t3.y, t1.y - t3.x);
    const float2 O3 = make_float2(t1.x - t3.y, t1.y + t3.x);
    const float2 wO1 = make_float2(C * (O1.x + O1.y), C * (O1.y - O1.x));
    const float2 w3O3 = make_float2(C * (O3.y - O3.x), -C * (O3.x + O3.y));
    const float2 mO2 = make_float2(O2.y, -O2.x);
    const float2 y0 = CADD(E0, O0), y4 = CSUB(E0, O0);
    const float2 y1 = CADD(E1, wO1), y5 = CSUB(E1, wO1);
    const float2 y2 = CADD(E2, mO2), y6 = CSUB(E2, mO2);
    const float2 y3 = CADD(E3, w3O3), y7 = CSUB(E3, w3O3);
    z[base]         = y0;
    z[base + Q]     = cmul(y1, W1);
    z[base + 2 * Q] = cmul(y2, W2);
    z[base + 3 * Q] = cmul(y3, W3);
    z[base + 4 * Q] = cmul(y4, W4);
    z[base + 5 * Q] = cmul(y5, W5);
    z[base + 6 * Q] = cmul(y6, W6);
    z[base + 7 * Q] = cmul(y7, W7);
  }
  __syncthreads();                                    // barrier 4
  // ---- forward radix-8 stages Q=32, Q=4 (wave-local: [512w, 512w+512)) ----
#pragma unroll
  for (int st = 0; st < 2; ++st) {
    const int Q = (st == 0) ? 32 : 4;
    const int j = tid & (Q - 1);
    const int base = ((tid & ~(Q - 1)) << 3) + j;
    const float2 x0 = z[base],         x1 = z[base + Q];
    const float2 x2 = z[base + 2 * Q], x3 = z[base + 3 * Q];
    const float2 x4 = z[base + 4 * Q], x5 = z[base + 5 * Q];
    const float2 x6 = z[base + 6 * Q], x7 = z[base + 7 * Q];
    const float2 W1 = tw[4 * Q + j], W2 = tw[2 * Q + j], W4 = tw[Q + j];
    const float2 W3 = cmul(W1, W2);
    const float2 W5 = cmul(W1, W4);
    const float2 W6 = cmul(W2, W4);
    const float2 W7 = cmul(W3, W4);
    const float2 s0 = CADD(x0, x4), s1 = CSUB(x0, x4);
    const float2 s2 = CADD(x2, x6), s3 = CSUB(x2, x6);
    const float2 E0 = CADD(s0, s2), E2 = CSUB(s0, s2);
    const float2 E1 = make_float2(s1.x + s3.y, s1.y - s3.x);
    const float2 E3 = make_float2(s1.x - s3.y, s1.y + s3.x);
    const float2 t0 = CADD(x1, x5), t1 = CSUB(x1, x5);
    const float2 t2 = CADD(x3, x7), t3 = CSUB(x3, x7);
    const float2 O0 = CADD(t0, t2), O2 = CSUB(t0, t2);
    const float2 O1 = make_float2(t1.x + t3.y, t1.y - t3.x);
    const float2 O3 = make_float2(t1.x - t3.y, t1.y + t3.x);
    const float2 wO1 = make_float2(C * (O1.x + O1.y), C * (O1.y - O1.x));
    const float2 w3O3 = make_float2(C * (O3.y - O3.x), -C * (O3.x + O3.y));
    const float2 mO2 = make_float2(O2.y, -O2.x);
    const float2 y0 = CADD(E0, O0), y4 = CSUB(E0, O0);
    const float2 y1 = CADD(E1, wO1), y5 = CSUB(E1, wO1);
    const float2 y2 = CADD(E2, mO2), y6 = CSUB(E2, mO2);
    const float2 y3 = CADD(E3, w3O3), y7 = CSUB(E3, w3O3);
    z[base]         = y0;
    z[base + Q]     = cmul(y1, W1);
    z[base + 2 * Q] = cmul(y2, W2);
    z[base + 3 * Q] = cmul(y3, W3);
    z[base + 4 * Q] = cmul(y4, W4);
    z[base + 5 * Q] = cmul(y5, W5);
    z[base + 6 * Q] = cmul(y6, W6);
    z[base + 7 * Q] = cmul(y7, W7);
    __builtin_amdgcn_wave_barrier();   // compiler fence; DS in-order per wave
  }
  // ---- forward radix-4 stage (Q=1), wave-local: bf in [128w, 128w+128) ----
#pragma unroll
  for (int h = 0; h < 2; ++h) {
    const int bf = 128 * wv + lane + 64 * h;
    const int base = bf << 2;
    const float2 x0 = z[base], x1 = z[base + 1];
    const float2 x2 = z[base + 2], x3 = z[base + 3];
    const float2 t0 = CADD(x0, x2), t1 = CSUB(x0, x2);
    const float2 t2 = CADD(x1, x3), t3 = CSUB(x1, x3);
    z[base]     = CADD(t0, t2);
    z[base + 1] = make_float2(t1.x + t3.y, t1.y - t3.x);
    z[base + 2] = CSUB(t0, t2);
    z[base + 3] = make_float2(t1.x - t3.y, t1.y + t3.x);
  }
  __builtin_amdgcn_wave_barrier();
  // ---- Hilbert mask, wave-local: pp in [512w, 512w+512) ----
#pragma unroll
  for (int i = 0; i < 8; ++i) {
    const int pp = 512 * wv + lane + 64 * i;
    if (pp != 0 && pp != 2) {
      if (pp & 2) { z[pp] = make_float2(0.f, 0.f); }
      else        { float2 v = z[pp]; z[pp] = make_float2(2.f * v.x, 2.f * v.y); }
    }
  }
  __builtin_amdgcn_wave_barrier();
  // ---- inverse radix-4 stage (Q=1), wave-local ----
#pragma unroll
  for (int h = 0; h < 2; ++h) {
    const int bf = 128 * wv + lane + 64 * h;
    const int base = bf << 2;
    const float2 u0 = z[base], u1 = z[base + 1];
    const float2 u2 = z[base + 2], u3 = z[base + 3];
    const float2 t0 = CADD(u0, u2), t1 = CSUB(u0, u2);
    const float2 t2 = CADD(u1, u3), t3 = CSUB(u1, u3);
    z[base]     = CADD(t0, t2);
    z[base + 1] = make_float2(t1.x - t3.y, t1.y + t3.x);
    z[base + 2] = CSUB(t0, t2);
    z[base + 3] = make_float2(t1.x + t3.y, t1.y - t3.x);
  }
  __builtin_amdgcn_wave_barrier();
  // ---- inverse radix-8 stages Q=4, Q=32 (wave-local) ----
#pragma unroll
  for (int st = 0; st < 2; ++st) {
    const int Q = (st == 0) ? 4 : 32;
    const int j = tid & (Q - 1);
    const int base = ((tid & ~(Q - 1)) << 3) + j;
    const float2 W1 = tw[4 * Q + j], W2 = tw[2 * Q + j], W4 = tw[Q + j];
    const float2 W3 = cmul(W1, W2);
    const float2 W5 = cmul(W1, W4);
    const float2 W6 = cmul(W2, W4);
    const float2 W7 = cmul(W3, W4);
    const float2 u0 = z[base];
    const float2 u1 = cmulc(z[base + Q], W1);
    const float2 u2 = cmulc(z[base + 2 * Q], W2);
    const float2 u3 = cmulc(z[base + 3 * Q], W3);
    const float2 u4 = cmulc(z[base + 4 * Q], W4);
    const float2 u5 = cmulc(z[base + 5 * Q], W5);
    const float2 u6 = cmulc(z[base + 6 * Q], W6);
    const float2 u7 = cmulc(z[base + 7 * Q], W7);
    const float2 s0 = CADD(u0, u4), s1 = CSUB(u0, u4);
    const float2 s2 = CADD(u2, u6), s3 = CSUB(u2, u6);
    const float2 E0 = CADD(s0, s2), E2 = CSUB(s0, s2);
    const float2 E1 = make_float2(s1.x - s3.y, s1.y + s3.x);
    const float2 E3 = make_float2(s1.x + s3.y, s1.y - s3.x);
    const float2 t0 = CADD(u1, u5), t1 = CSUB(u1, u5);
    const float2 t2 = CADD(u3, u7), t3 = CSUB(u3, u7);
    const float2 O0 = CADD(t0, t2), O2 = CSUB(t0, t2);
    const float2 O1 = make_float2(t1.x - t3.y, t1.y + t3.x);
    const float2 O3 = make_float2(t1.x + t3.y, t1.y - t3.x);
    const float2 nO1 = make_float2(C * (O1.x - O1.y), C * (O1.x + O1.y));
    const float2 n3O3 = make_float2(-C * (O3.x + O3.y), C * (O3.x - O3.y));
    const float2 iO2 = make_float2(-O2.y, O2.x);
    z[base]         = CADD(E0, O0);
    z[base + 4 * Q] = CSUB(E0, O0);
    z[base + Q]     = CADD(E1, nO1);
    z[base + 5 * Q] = CSUB(E1, nO1);
    z[base + 2 * Q] = CADD(E2, iO2);
    z[base + 6 * Q] = CSUB(E2, iO2);
    z[base + 3 * Q] = CADD(E3, n3O3);
    z[base + 7 * Q] = CSUB(E3, n3O3);
    __builtin_amdgcn_wave_barrier();
  }
  __syncthreads();                                    // barrier 5
  // ---- inverse radix-8 stage Q=256 (cross-wave) ----
  {
    const int Q = 256;
    const int j = tid & (Q - 1);
    const int base = ((tid & ~(Q - 1)) << 3) + j;
    const float2 W1 = tw[4 * Q + j], W2 = tw[2 * Q + j], W4 = tw[Q + j];
    const float2 W3 = cmul(W1, W2);
    const float2 W5 = cmul(W1, W4);
    const float2 W6 = cmul(W2, W4);
    const float2 W7 = cmul(W3, W4);
    const float2 u0 = z[base];
    const float2 u1 = cmulc(z[base + Q], W1);
    const float2 u2 = cmulc(z[base + 2 * Q], W2);
    const float2 u3 = cmulc(z[base + 3 * Q], W3);
    const float2 u4 = cmulc(z[base + 4 * Q], W4);
    const float2 u5 = cmulc(z[base + 5 * Q], W5);
    const float2 u6 = cmulc(z[base + 6 * Q], W6);
    const float2 u7 = cmulc(z[base + 7 * Q], W7);
    const float2 s0 = CADD(u0, u4), s1 = CSUB(u0, u4);
    const float2 s2 = CADD(u2, u6), s3 = CSUB(u2, u6);
    const float2 E0 = CADD(s0, s2), E2 = CSUB(s0, s2);
    const float2 E1 = make_float2(s1.x - s3.y, s1.y + s3.x);
    const float2 E3 = make_float2(s1.x + s3.y, s1.y - s3.x);
    const float2 t0 = CADD(u1, u5), t1 = CSUB(u1, u5);
    const float2 t2 = CADD(u3, u7), t3 = CSUB(u3, u7);
    const float2 O0 = CADD(t0, t2), O2 = CSUB(t0, t2);
    const float2 O1 = make_float2(t1.x - t3.y, t1.y + t3.x);
    const float2 O3 = make_float2(t1.x + t3.y, t1.y - t3.x);
    const float2 nO1 = make_float2(C * (O1.x - O1.y), C * (O1.x + O1.y));
    const float2 n3O3 = make_float2(-C * (O3.x + O3.y), C * (O3.x - O3.y));
    const float2 iO2 = make_float2(-O2.y, O2.x);
    z[base]         = CADD(E0, O0);
    z[base + 4 * Q] = CSUB(E0, O0);
    z[base + Q]     = CADD(E1, nO1);
    z[base + 5 * Q] = CSUB(E1, nO1);
    z[base + 2 * Q] = CADD(E2, iO2);
    z[base + 6 * Q] = CSUB(E2, iO2);
    z[base + 3 * Q] = CADD(E3, n3O3);
    z[base + 7 * Q] = CSUB(E3, n3O3);
  }
  __syncthreads();                                    // barrier 6
  // ---- epilogue: phase for o1, amp for o2; x1,x2 still in registers ----
  float* out1 = filt + ((size_t)n * NF + o1) * TT;
  float* out2 = filt + ((size_t)n * NF + o2) * TT;
  const float invN = 1.0f / 2048.0f;
  float phA[4], phB[4], amA[4], amB[4];
#pragma unroll
  for (int r = 0; r < 4; ++r) {
    float2 wvA = z[bA + r];
    float h1 = wvA.y * invN - acc2A[r];
    float h2 = acc1A[r] - wvA.x * invN;
    phA[r] = atan2f(h1, acc1A[r]);
    amA[r] = sqrtf(fmaf(acc2A[r], acc2A[r], h2 * h2));
    float2 wvB = z[bB + r];
    float g1 = wvB.y * invN - acc2B[r];
    float g2 = acc1B[r] - wvB.x * invN;
    phB[r] = atan2f(g1, acc1B[r]);
    amB[r] = sqrtf(fmaf(acc2B[r], acc2B[r], g2 * g2));
  }
  *(float4*)&out1[bA] = make_float4(phA[0], phA[1], phA[2], phA[3]);
  *(float4*)&out1[bB] = make_float4(phB[0], phB[1], phB[2], phB[3]);
  *(float4*)&out2[bA] = make_float4(amA[0], amA[1], amA[2], amA[3]);
  *(float4*)&out2[bB] = make_float4(amB[0], amB[1], amB[2], amB[3]);
}

// ---------------------------------------------------------------------------
// Kernel C: binned MI via MFMA (unchanged: 4 waves/block K-split, verified
// 16x16x32 layouts, 3-way exact bf16 split, counts via ones-row).
// ---------------------------------------------------------------------------
__global__ __launch_bounds__(256) void mi_kernel(const float* __restrict__ filt,
                                                 float* __restrict__ mi) {
  __shared__ __align__(16) unsigned int idx32[512];  // 4 bins/dword
  __shared__ float Cp[4][12][19];                    // per-wave partial C
  const int tid = threadIdx.x;
  const int wave = tid >> 6;
  const int lane = tid & 63;
  const int blk = blockIdx.x;           // bc*40 + jp
  const int bc = blk / 40, jp = blk % 40;
  const float* ph = filt + ((size_t)(bc * 4 + jp / 10) * NF + (jp % 10)) * TT;
  for (int g = tid; g < 512; g += 256) {
    float4 v = *(const float4*)&ph[4 * g];
    float vv[4] = {v.x, v.y, v.z, v.w};
    unsigned int packed = 0;
#pragma unroll
    for (int j = 0; j < 4; ++j) {
      int b = (int)floorf((vv[j] + 3.14159274f) / 6.2831855f * 18.0f);
      b = b < 0 ? 0 : (b > 17 ? 17 : b);
      packed |= ((unsigned int)b) << (8 * j);
    }
    idx32[g] = packed;
  }
  __syncthreads();
  const int n16 = lane & 15;    // A row m / B col n / C col
  const int quad = lane >> 4;   // k-quad (0..3)
  const int aband = n16 < 10 ? n16 : 9;
  const int ja = (jp & 3) + 4 * aband;   // scrambled amp row, same s'
  const float* aptr = filt + ((size_t)(bc * 4 + ja / 10) * NF + 10 + (ja % 10)) * TT
                      + quad * 8;
  const bool isAmp = (n16 < 10);
  const bool isOne = (n16 == 10);
  f32x4 acc0 = {0.f, 0.f, 0.f, 0.f};     // bins 0..15
  f32x4 acc1 = {0.f, 0.f, 0.f, 0.f};     // bins 16..17 (cols 16+n16)
  const int s0 = wave * 16, s1 = s0 + 16;
  float4 p0 = *(const float4*)(aptr + s0 * 32);
  float4 p1 = *(const float4*)(aptr + s0 * 32 + 4);
  for (int s = s0; s < s1; ++s) {
    float4 c0 = p0, c1 = p1;
    if (s < s1 - 1) {
      p0 = *(const float4*)(aptr + (s + 1) * 32);
      p1 = *(const float4*)(aptr + (s + 1) * 32 + 4);
    }
    float a[8] = {c0.x, c0.y, c0.z, c0.w, c1.x, c1.y, c1.z, c1.w};
    short8 ah, am_, al;
#pragma unroll
    for (int j = 0; j < 8; ++j) {
      float v = isAmp ? a[j] : (isOne ? 1.0f : 0.0f);
      unsigned int u = __float_as_uint(v);
      float h = __uint_as_float(u & 0xFFFF0000u);
      float r1 = v - h;                       // exact (<=16 sig bits)
      unsigned int u2 = __float_as_uint(r1);
      float md = __uint_as_float(u2 & 0xFFFF0000u);
      float r2 = r1 - md;                     // exact (<=8 sig bits)
      unsigned int u3 = __float_as_uint(r2);
      ah[j] = (short)(u >> 16);
      am_[j] = (short)(u2 >> 16);
      al[j] = (short)(u3 >> 16);
    }
    const int dw = s * 8 + quad * 2;
    unsigned int d0 = idx32[dw], d1 = idx32[dw + 1];
    short8 b0, b1;
#pragma unroll
    for (int j = 0; j < 8; ++j) {
      unsigned int byte = ((j < 4 ? d0 : d1) >> ((j & 3) * 8)) & 0xFFu;
      b0[j] = (byte == (unsigned int)n16) ? (short)0x3F80 : (short)0;
      b1[j] = (byte == (unsigned int)(n16 + 16)) ? (short)0x3F80 : (short)0;
    }
    acc0 = __builtin_amdgcn_mfma_f32_16x16x32_bf16(ah, b0, acc0, 0, 0, 0);
    acc0 = __builtin_amdgcn_mfma_f32_16x16x32_bf16(am_, b0, acc0, 0, 0, 0);
    acc0 = __builtin_amdgcn_mfma_f32_16x16x32_bf16(al, b0, acc0, 0, 0, 0);
    acc1 = __builtin_amdgcn_mfma_f32_16x16x32_bf16(ah, b1, acc1, 0, 0, 0);
    acc1 = __builtin_amdgcn_mfma_f32_16x16x32_bf16(am_, b1, acc1, 0, 0, 0);
    acc1 = __builtin_amdgcn_mfma_f32_16x16x32_bf16(al, b1, acc1, 0, 0, 0);
  }
#pragma unroll
  for (int r = 0; r < 4; ++r) {
    int row = quad * 4 + r;
    if (row < 11) {
      Cp[wave][row][n16] = acc0[r];
      if (n16 < 2) Cp[wave][row][16 + n16] = acc1[r];
    }
  }
  __syncthreads();
  if (tid < 10) {
    float tot = 0.f, mb_[18];
#pragma unroll
    for (int b = 0; b < 18; ++b) {
      float s = Cp[0][tid][b] + Cp[1][tid][b] + Cp[2][tid][b] + Cp[3][tid][b];
      float c = Cp[0][10][b] + Cp[1][10][b] + Cp[2][10][b] + Cp[3][10][b];
      float mb = s / fmaxf(c, 1.0f);
      mb_[b] = mb; tot += mb;
    }
    tot = fmaxf(tot, 1e-12f);
    float s = 0.f;
#pragma unroll
    for (int b = 0; b < 18; ++b) {
      float pb = mb_[b] / tot;
      s += pb * logf(fmaxf(pb, 1e-12f));
    }
    const float LOGN = 2.8903717578961645f; // log(18)
    mi[(size_t)blk * 10 + tid] = (LOGN + s) / LOGN;
  }
}

// ---------------------------------------------------------------------------
// Kernel D: mean over the scrambled s' axis -> out (4,8,10,10)
// ---------------------------------------------------------------------------
__global__ void out_kernel(const float* __restrict__ mi, float* __restrict__ out) {
  int i = blockIdx.x * 256 + threadIdx.x;
  if (i < 3200) {
    int a = i % 10, p = (i / 10) % 10, bc = i / 100;
    float s = 0.f;
    for (int sp = 0; sp < 4; ++sp)
      s += mi[((size_t)(bc * 40 + p * 4 + sp)) * 10 + a];
    out[i] = 0.25f * s;
  }
}

extern "C" void kernel_launch(void* const* d_in, const int* in_sizes, int n_in,
                              void* d_out, int out_size, void* d_ws, size_t ws_size,
                              hipStream_t stream) {
  (void)in_sizes; (void)n_in; (void)out_size; (void)ws_size;
  const float* x = (const float*)d_in[0];     // (4,8,4,2048) fp32
  const float* ker = (const float*)d_in[1];   // (20,769) fp32
  float* out = (float*)d_out;                 // 3200 fp32
  float* filt = (float*)d_ws;                 // 128*20*2048 fp32 (~21 MB)
  float* mi = filt + (size_t)NS * NF * TT;    // 12800 fp32
  float2* tw = (float2*)(mi + 12800);         // 2048 float2 (16 KB)
  float* hsym = (float*)(tw + TT);            // 20*784 fp32
  int* rng = (int*)(hsym + NF * 784);         // 40 ints

  prep_kernel<<<28, 256, 0, stream>>>(ker, tw, hsym, rng);
  convhil_kernel<<<NS * 10, 256, 0, stream>>>(x, hsym, rng, tw, filt);
  mi_kernel<<<32 * 40, 256, 0, stream>>>(filt, mi);
  out_kernel<<<(3200 + 255) / 256, 256, 0, stream>>>(mi, out);
}

// Round 21
// 127.611 us; speedup vs baseline: 1.1139x; 1.0091x over previous
//
#include <hip/hip_runtime.h>
#include <math.h>

#define TT 2048
#define LK 769
#define NF 20
#define NS 128
#define NB 18

typedef __attribute__((ext_vector_type(8))) short short8;
typedef __attribute__((ext_vector_type(4))) float f32x4;

__device__ __forceinline__ float2 cmul(float2 a, float2 b) {
  return make_float2(a.x * b.x - a.y * b.y, a.x * b.y + a.y * b.x);
}
__device__ __forceinline__ float2 cmulc(float2 a, float2 b) {  // a * conj(b)
  return make_float2(a.x * b.x + a.y * b.y, a.y * b.x - a.x * b.y);
}
#define CADD(a, b) make_float2((a).x + (b).x, (a).y + (b).y)
#define CSUB(a, b) make_float2((a).x - (b).x, (a).y - (b).y)

// ---------------------------------------------------------------------------
// Kernel P: one-time prep: twiddles + symmetrized filters + 8-aligned
// nonzero ranges. R21: also zeroes d_out (3200 floats) so mi_kernel can
// accumulate the s'-mean directly with atomicAdd (out_kernel removed).
// ---------------------------------------------------------------------------
__global__ __launch_bounds__(256) void prep_kernel(const float* __restrict__ ker,
                                                   float2* __restrict__ tw,
                                                   float* __restrict__ hsym,
                                                   int* __restrict__ rng,
                                                   float* __restrict__ out) {
  __shared__ int red[4][2];
  const int blk = blockIdx.x;
  const int tid = threadIdx.x;
  if (blk < 8) {
    int i = blk * 256 + tid;
    if (i == 0) { tw[0] = make_float2(1.f, 0.f); }
    else {
      int half = 1 << (31 - __clz(i));
      int j = i - half;
      float ang = -3.14159265358979323846f * (float)j / (float)half;
      float s, c;
      sincosf(ang, &s, &c);
      tw[i] = make_float2(c, s);
    }
    // blocks 0..12 also zero out[0..3200) (13*256 = 3328 >= 3200)
    int oi = blk * 256 + tid;
    if (oi < 3200) out[oi] = 0.f;
    return;
  }
  if (blk >= 8 && blk < 13) {
    int oi = blk * 256 + tid;
    if (oi < 3200) out[oi] = 0.f;
  }
  if (blk < 13 && blk >= 8) { /* fallthrough to filter work below with o = blk-8 */ }
  const int o = blk - 8;
  if (o >= NF) return;
  const float* kr = ker + o * LK;
  int k0 = 784, k1 = 0;
  for (int k = tid; k < 784; k += 256) {
    float v = 0.f;
    if (k < LK) v = 0.5f * (kr[k] + kr[LK - 1 - k]);
    hsym[o * 784 + k] = v;
    if (v != 0.f) { k0 = min(k0, k); k1 = max(k1, k + 1); }
  }
#pragma unroll
  for (int off = 32; off > 0; off >>= 1) {
    k0 = min(k0, __shfl_down(k0, off));
    k1 = max(k1, __shfl_down(k1, off));
  }
  if ((tid & 63) == 0) { red[tid >> 6][0] = k0; red[tid >> 6][1] = k1; }
  __syncthreads();
  if (tid == 0) {
    k0 = min(min(red[0][0], red[1][0]), min(red[2][0], red[3][0]));
    k1 = max(max(red[0][1], red[1][1]), max(red[2][1], red[3][1]));
    rng[2 * o] = k0 & ~7;              // 8-aligned (extra taps exact zeros)
    rng[2 * o + 1] = (k1 + 7) & ~7;
  }
}

// ---------------------------------------------------------------------------
// Kernel A: FUSED conv + Hilbert (R20 structure: scalar taps, 8*8*8*4 FFT,
// wave-synchronous inner stages). Unchanged this round.
// ---------------------------------------------------------------------------
__global__ __launch_bounds__(256) void convhil_kernel(const float* __restrict__ x,
                                                      const float* __restrict__ hsym,
                                                      const int* __restrict__ rng,
                                                      const float2* __restrict__ tw,
                                                      float* __restrict__ filt) {
  __shared__ __align__(16) float smem[4096];   // w[2832]; z (4096 floats) overlays
  float* w   = smem;
  float2* z  = (float2*)smem;                  // 2048 float2
  const int tid = threadIdx.x;
  const int wv = tid >> 6;                     // wave id (0..3)
  const int lane = tid & 63;
  const int ord = blockIdx.x;
  const int p = ord / NS;                   // 0..9, longest pair first
  const int n = ord % NS;
  const int o1 = p;                          // pha band
  const int o2 = 10 + (9 - p);               // amp band (short with long)
  const float* xr = x + n * TT;
  for (int j = tid; j < 2832; j += 256) {
    float v = 0.f;
    if (j < 2816) {
      int m = j - 384;              // spad[j+384] -> original index (j+384)-768
      if (m < 0) m = -m;            // reflect (edge excluded)
      if (m > 2047) m = 4094 - m;
      v = xr[m];
    }
    w[j] = v;
  }
  const float* h1g = hsym + o1 * 784;        // uniform base -> scalar loads
  const float* h2g = hsym + o2 * 784;
  const int A0 = rng[2 * o1], A1 = rng[2 * o1 + 1];   // uniform -> scalar loads
  const int B0 = rng[2 * o2], B1 = rng[2 * o2 + 1];
  const int U0 = min(A0, B0);
  const int U1 = max(A1, B1);
  __syncthreads();                                    // barrier 1

  const int bA = 4 * tid;           // group A outputs [bA, bA+4)
  const int bB = 1024 + 4 * tid;    // group B outputs [bB, bB+4)
  float acc1A[4], acc1B[4], acc2A[4], acc2B[4];
#pragma unroll
  for (int r = 0; r < 4; ++r) { acc1A[r] = 0.f; acc1B[r] = 0.f; acc2A[r] = 0.f; acc2B[r] = 0.f; }
  if (U0 < U1) {
    // rolling window: a0..a2 cover w[bA+k .. bA+k+12)
    float4 a0 = *(const float4*)&w[bA + U0];
    float4 a1 = *(const float4*)&w[bA + U0 + 4];
    float4 a2 = *(const float4*)&w[bA + U0 + 8];
    float4 b0 = *(const float4*)&w[bB + U0];
    float4 b1 = *(const float4*)&w[bB + U0 + 4];
    float4 b2 = *(const float4*)&w[bB + U0 + 8];
    float4 h1a = *(const float4*)&h1g[U0];     // uniform -> s_load_dwordx4
    float4 h1b = *(const float4*)&h1g[U0 + 4];
    float4 h2a = *(const float4*)&h2g[U0];
    float4 h2b = *(const float4*)&h2g[U0 + 4];
    for (int k = U0; k < U1; k += 8) {
      float4 a3 = *(const float4*)&w[bA + k + 12];
      float4 a4 = *(const float4*)&w[bA + k + 16];
      float4 b3 = *(const float4*)&w[bB + k + 12];
      float4 b4 = *(const float4*)&w[bB + k + 16];
      float4 h1an = *(const float4*)&h1g[k + 8];    // scalar prefetch
      float4 h1bn = *(const float4*)&h1g[k + 12];
      float4 h2an = *(const float4*)&h2g[k + 8];
      float4 h2bn = *(const float4*)&h2g[k + 12];
      float wa[11] = {a0.x, a0.y, a0.z, a0.w, a1.x, a1.y, a1.z, a1.w,
                      a2.x, a2.y, a2.z};
      float wb[11] = {b0.x, b0.y, b0.z, b0.w, b1.x, b1.y, b1.z, b1.w,
                      b2.x, b2.y, b2.z};
      float h1[8] = {h1a.x, h1a.y, h1a.z, h1a.w, h1b.x, h1b.y, h1b.z, h1b.w};
      float h2[8] = {h2a.x, h2a.y, h2a.z, h2a.w, h2b.x, h2b.y, h2b.z, h2b.w};
      if (k >= A0 && k < A1) {
#pragma unroll
        for (int r = 0; r < 4; ++r) {
#pragma unroll
          for (int j = 0; j < 8; ++j) {
            acc1A[r] = fmaf(h1[j], wa[r + j], acc1A[r]);
            acc1B[r] = fmaf(h1[j], wb[r + j], acc1B[r]);
          }
        }
      }
      if (k >= B0 && k < B1) {
#pragma unroll
        for (int r = 0; r < 4; ++r) {
#pragma unroll
          for (int j = 0; j < 8; ++j) {
            acc2A[r] = fmaf(h2[j], wa[r + j], acc2A[r]);
            acc2B[r] = fmaf(h2[j], wb[r + j], acc2B[r]);
          }
        }
      }
      a0 = a2; a1 = a3; a2 = a4;
      b0 = b2; b1 = b3; b2 = b4;
      h1a = h1an; h1b = h1bn;
      h2a = h2an; h2b = h2bn;
    }
  }
  // ---- hand off to FFT: z = out1 + i*out2 (overlays dead w region) ----
  __syncthreads();                                    // barrier 2
#pragma unroll
  for (int r = 0; r < 4; ++r) {
    z[bA + r] = make_float2(acc1A[r], acc2A[r]);
    z[bB + r] = make_float2(acc1B[r], acc2B[r]);
  }
  __syncthreads();                                    // barrier 3
  const float C = 0.70710678118654752f;
  // ---- forward radix-8 stage Q=256 (cross-wave) ----
  {
    const int Q = 256;
    const int j = tid & (Q - 1);
    const int base = ((tid & ~(Q - 1)) << 3) + j;
    const float2 x0 = z[base],         x1 = z[base + Q];
    const float2 x2 = z[base + 2 * Q], x3 = z[base + 3 * Q];
    const float2 x4 = z[base + 4 * Q], x5 = z[base + 5 * Q];
    const float2 x6 = z[base + 6 * Q], x7 = z[base + 7 * Q];
    const float2 W1 = tw[4 * Q + j], W2 = tw[2 * Q + j], W4 = tw[Q + j];
    const float2 W3 = cmul(W1, W2);
    const float2 W5 = cmul(W1, W4);
    const float2 W6 = cmul(W2, W4);
    const float2 W7 = cmul(W3, W4);
    const float2 s0 = CADD(x0, x4), s1 = CSUB(x0, x4);
    const float2 s2 = CADD(x2, x6), s3 = CSUB(x2, x6);
    const float2 E0 = CADD(s0, s2), E2 = CSUB(s0, s2);
    const float2 E1 = make_float2(s1.x + s3.y, s1.y - s3.x);
    const float2 E3 = make_float2(s1.x - s3.y, s1.y + s3.x);
    const float2 t0 = CADD(x1, x5), t1 = CSUB(x1, x5);
    const float2 t2 = CADD(x3, x7), t3 = CSUB(x3, x7);
    const float2 O0 = CADD(t0, t2), O2 = CSUB(t0, t2);
    const float2 O1 = make_float2(t1.x + t3.y, t1.y - t3.x);
    const float2 O3 = make_float2(t1.x - t3.y, t1.y + t3.x);
    const float2 wO1 = make_float2(C * (O1.x + O1.y), C * (O1.y - O1.x));
    const float2 w3O3 = make_float2(C * (O3.y - O3.x), -C * (O3.x + O3.y));
    const float2 mO2 = make_float2(O2.y, -O2.x);
    const float2 y0 = CADD(E0, O0), y4 = CSUB(E0, O0);
    const float2 y1 = CADD(E1, wO1), y5 = CSUB(E1, wO1);
    const float2 y2 = CADD(E2, mO2), y6 = CSUB(E2, mO2);
    const float2 y3 = CADD(E3, w3O3), y7 = CSUB(E3, w3O3);
    z[base]         = y0;
    z[base + Q]     = cmul(y1, W1);
    z[base + 2 * Q] = cmul(y2, W2);
    z[base + 3 * Q] = cmul(y3, W3);
    z[base + 4 * Q] = cmul(y4, W4);
    z[base + 5 * Q] = cmul(y5, W5);
    z[base + 6 * Q] = cmul(y6, W6);
    z[base + 7 * Q] = cmul(y7, W7);
  }
  __syncthreads();                                    // barrier 4
  // ---- forward radix-8 stages Q=32, Q=4 (wave-local: [512w, 512w+512)) ----
#pragma unroll
  for (int st = 0; st < 2; ++st) {
    const int Q = (st == 0) ? 32 : 4;
    const int j = tid & (Q - 1);
    const int base = ((tid & ~(Q - 1)) << 3) + j;
    const float2 x0 = z[base],         x1 = z[base + Q];
    const float2 x2 = z[base + 2 * Q], x3 = z[base + 3 * Q];
    const float2 x4 = z[base + 4 * Q], x5 = z[base + 5 * Q];
    const float2 x6 = z[base + 6 * Q], x7 = z[base + 7 * Q];
    const float2 W1 = tw[4 * Q + j], W2 = tw[2 * Q + j], W4 = tw[Q + j];
    const float2 W3 = cmul(W1, W2);
    const float2 W5 = cmul(W1, W4);
    const float2 W6 = cmul(W2, W4);
    const float2 W7 = cmul(W3, W4);
    const float2 s0 = CADD(x0, x4), s1 = CSUB(x0, x4);
    const float2 s2 = CADD(x2, x6), s3 = CSUB(x2, x6);
    const float2 E0 = CADD(s0, s2), E2 = CSUB(s0, s2);
    const float2 E1 = make_float2(s1.x + s3.y, s1.y - s3.x);
    const float2 E3 = make_float2(s1.x - s3.y, s1.y + s3.x);
    const float2 t0 = CADD(x1, x5), t1 = CSUB(x1, x5);
    const float2 t2 = CADD(x3, x7), t3 = CSUB(x3, x7);
    const float2 O0 = CADD(t0, t2), O2 = CSUB(t0, t2);
    const float2 O1 = make_float2(t1.x + t3.y, t1.y - t3.x);
    const float2 O3 = make_float2(t1.x - t3.y, t1.y + t3.x);
    const float2 wO1 = make_float2(C * (O1.x + O1.y), C * (O1.y - O1.x));
    const float2 w3O3 = make_float2(C * (O3.y - O3.x), -C * (O3.x + O3.y));
    const float2 mO2 = make_float2(O2.y, -O2.x);
    const float2 y0 = CADD(E0, O0), y4 = CSUB(E0, O0);
    const float2 y1 = CADD(E1, wO1), y5 = CSUB(E1, wO1);
    const float2 y2 = CADD(E2, mO2), y6 = CSUB(E2, mO2);
    const float2 y3 = CADD(E3, w3O3), y7 = CSUB(E3, w3O3);
    z[base]         = y0;
    z[base + Q]     = cmul(y1, W1);
    z[base + 2 * Q] = cmul(y2, W2);
    z[base + 3 * Q] = cmul(y3, W3);
    z[base + 4 * Q] = cmul(y4, W4);
    z[base + 5 * Q] = cmul(y5, W5);
    z[base + 6 * Q] = cmul(y6, W6);
    z[base + 7 * Q] = cmul(y7, W7);
    __builtin_amdgcn_wave_barrier();   // compiler fence; DS in-order per wave
  }
  // ---- forward radix-4 stage (Q=1), wave-local: bf in [128w, 128w+128) ----
#pragma unroll
  for (int h = 0; h < 2; ++h) {
    const int bf = 128 * wv + lane + 64 * h;
    const int base = bf << 2;
    const float2 x0 = z[base], x1 = z[base + 1];
    const float2 x2 = z[base + 2], x3 = z[base + 3];
    const float2 t0 = CADD(x0, x2), t1 = CSUB(x0, x2);
    const float2 t2 = CADD(x1, x3), t3 = CSUB(x1, x3);
    z[base]     = CADD(t0, t2);
    z[base + 1] = make_float2(t1.x + t3.y, t1.y - t3.x);
    z[base + 2] = CSUB(t0, t2);
    z[base + 3] = make_float2(t1.x - t3.y, t1.y + t3.x);
  }
  __builtin_amdgcn_wave_barrier();
  // ---- Hilbert mask, wave-local: pp in [512w, 512w+512) ----
#pragma unroll
  for (int i = 0; i < 8; ++i) {
    const int pp = 512 * wv + lane + 64 * i;
    if (pp != 0 && pp != 2) {
      if (pp & 2) { z[pp] = make_float2(0.f, 0.f); }
      else        { float2 v = z[pp]; z[pp] = make_float2(2.f * v.x, 2.f * v.y); }
    }
  }
  __builtin_amdgcn_wave_barrier();
  // ---- inverse radix-4 stage (Q=1), wave-local ----
#pragma unroll
  for (int h = 0; h < 2; ++h) {
    const int bf = 128 * wv + lane + 64 * h;
    const int base = bf << 2;
    const float2 u0 = z[base], u1 = z[base + 1];
    const float2 u2 = z[base + 2], u3 = z[base + 3];
    const float2 t0 = CADD(u0, u2), t1 = CSUB(u0, u2);
    const float2 t2 = CADD(u1, u3), t3 = CSUB(u1, u3);
    z[base]     = CADD(t0, t2);
    z[base + 1] = make_float2(t1.x - t3.y, t1.y + t3.x);
    z[base + 2] = CSUB(t0, t2);
    z[base + 3] = make_float2(t1.x + t3.y, t1.y - t3.x);
  }
  __builtin_amdgcn_wave_barrier();
  // ---- inverse radix-8 stages Q=4, Q=32 (wave-local) ----
#pragma unroll
  for (int st = 0; st < 2; ++st) {
    const int Q = (st == 0) ? 4 : 32;
    const int j = tid & (Q - 1);
    const int base = ((tid & ~(Q - 1)) << 3) + j;
    const float2 W1 = tw[4 * Q + j], W2 = tw[2 * Q + j], W4 = tw[Q + j];
    const float2 W3 = cmul(W1, W2);
    const float2 W5 = cmul(W1, W4);
    const float2 W6 = cmul(W2, W4);
    const float2 W7 = cmul(W3, W4);
    const float2 u0 = z[base];
    const float2 u1 = cmulc(z[base + Q], W1);
    const float2 u2 = cmulc(z[base + 2 * Q], W2);
    const float2 u3 = cmulc(z[base + 3 * Q], W3);
    const float2 u4 = cmulc(z[base + 4 * Q], W4);
    const float2 u5 = cmulc(z[base + 5 * Q], W5);
    const float2 u6 = cmulc(z[base + 6 * Q], W6);
    const float2 u7 = cmulc(z[base + 7 * Q], W7);
    const float2 s0 = CADD(u0, u4), s1 = CSUB(u0, u4);
    const float2 s2 = CADD(u2, u6), s3 = CSUB(u2, u6);
    const float2 E0 = CADD(s0, s2), E2 = CSUB(s0, s2);
    const float2 E1 = make_float2(s1.x - s3.y, s1.y + s3.x);
    const float2 E3 = make_float2(s1.x + s3.y, s1.y - s3.x);
    const float2 t0 = CADD(u1, u5), t1 = CSUB(u1, u5);
    const float2 t2 = CADD(u3, u7), t3 = CSUB(u3, u7);
    const float2 O0 = CADD(t0, t2), O2 = CSUB(t0, t2);
    const float2 O1 = make_float2(t1.x - t3.y, t1.y + t3.x);
    const float2 O3 = make_float2(t1.x + t3.y, t1.y - t3.x);
    const float2 nO1 = make_float2(C * (O1.x - O1.y), C * (O1.x + O1.y));
    const float2 n3O3 = make_float2(-C * (O3.x + O3.y), C * (O3.x - O3.y));
    const float2 iO2 = make_float2(-O2.y, O2.x);
    z[base]         = CADD(E0, O0);
    z[base + 4 * Q] = CSUB(E0, O0);
    z[base + Q]     = CADD(E1, nO1);
    z[base + 5 * Q] = CSUB(E1, nO1);
    z[base + 2 * Q] = CADD(E2, iO2);
    z[base + 6 * Q] = CSUB(E2, iO2);
    z[base + 3 * Q] = CADD(E3, n3O3);
    z[base + 7 * Q] = CSUB(E3, n3O3);
    __builtin_amdgcn_wave_barrier();
  }
  __syncthreads();                                    // barrier 5
  // ---- inverse radix-8 stage Q=256 (cross-wave) ----
  {
    const int Q = 256;
    const int j = tid & (Q - 1);
    const int base = ((tid & ~(Q - 1)) << 3) + j;
    const float2 W1 = tw[4 * Q + j], W2 = tw[2 * Q + j], W4 = tw[Q + j];
    const float2 W3 = cmul(W1, W2);
    const float2 W5 = cmul(W1, W4);
    const float2 W6 = cmul(W2, W4);
    const float2 W7 = cmul(W3, W4);
    const float2 u0 = z[base];
    const float2 u1 = cmulc(z[base + Q], W1);
    const float2 u2 = cmulc(z[base + 2 * Q], W2);
    const float2 u3 = cmulc(z[base + 3 * Q], W3);
    const float2 u4 = cmulc(z[base + 4 * Q], W4);
    const float2 u5 = cmulc(z[base + 5 * Q], W5);
    const float2 u6 = cmulc(z[base + 6 * Q], W6);
    const float2 u7 = cmulc(z[base + 7 * Q], W7);
    const float2 s0 = CADD(u0, u4), s1 = CSUB(u0, u4);
    const float2 s2 = CADD(u2, u6), s3 = CSUB(u2, u6);
    const float2 E0 = CADD(s0, s2), E2 = CSUB(s0, s2);
    const float2 E1 = make_float2(s1.x - s3.y, s1.y + s3.x);
    const float2 E3 = make_float2(s1.x + s3.y, s1.y - s3.x);
    const float2 t0 = CADD(u1, u5), t1 = CSUB(u1, u5);
    const float2 t2 = CADD(u3, u7), t3 = CSUB(u3, u7);
    const float2 O0 = CADD(t0, t2), O2 = CSUB(t0, t2);
    const float2 O1 = make_float2(t1.x - t3.y, t1.y + t3.x);
    const float2 O3 = make_float2(t1.x + t3.y, t1.y - t3.x);
    const float2 nO1 = make_float2(C * (O1.x - O1.y), C * (O1.x + O1.y));
    const float2 n3O3 = make_float2(-C * (O3.x + O3.y), C * (O3.x - O3.y));
    const float2 iO2 = make_float2(-O2.y, O2.x);
    z[base]         = CADD(E0, O0);
    z[base + 4 * Q] = CSUB(E0, O0);
    z[base + Q]     = CADD(E1, nO1);
    z[base + 5 * Q] = CSUB(E1, nO1);
    z[base + 2 * Q] = CADD(E2, iO2);
    z[base + 6 * Q] = CSUB(E2, iO2);
    z[base + 3 * Q] = CADD(E3, n3O3);
    z[base + 7 * Q] = CSUB(E3, n3O3);
  }
  __syncthreads();                                    // barrier 6
  // ---- epilogue: phase for o1, amp for o2; x1,x2 still in registers ----
  float* out1 = filt + ((size_t)n * NF + o1) * TT;
  float* out2 = filt + ((size_t)n * NF + o2) * TT;
  const float invN = 1.0f / 2048.0f;
  float phA[4], phB[4], amA[4], amB[4];
#pragma unroll
  for (int r = 0; r < 4; ++r) {
    float2 wvA = z[bA + r];
    float h1 = wvA.y * invN - acc2A[r];
    float h2 = acc1A[r] - wvA.x * invN;
    phA[r] = atan2f(h1, acc1A[r]);
    amA[r] = sqrtf(fmaf(acc2A[r], acc2A[r], h2 * h2));
    float2 wvB = z[bB + r];
    float g1 = wvB.y * invN - acc2B[r];
    float g2 = acc1B[r] - wvB.x * invN;
    phB[r] = atan2f(g1, acc1B[r]);
    amB[r] = sqrtf(fmaf(acc2B[r], acc2B[r], g2 * g2));
  }
  *(float4*)&out1[bA] = make_float4(phA[0], phA[1], phA[2], phA[3]);
  *(float4*)&out1[bB] = make_float4(phB[0], phB[1], phB[2], phB[3]);
  *(float4*)&out2[bA] = make_float4(amA[0], amA[1], amA[2], amA[3]);
  *(float4*)&out2[bB] = make_float4(amB[0], amB[1], amB[2], amB[3]);
}

// ---------------------------------------------------------------------------
// Kernel C: binned MI via MFMA (4 waves/block K-split, verified 16x16x32
// layouts, 3-way exact bf16 split, counts via ones-row). R21: s'-mean folded
// in via device atomicAdd on d_out (zeroed by prep) — out_kernel removed.
// out layout: (bc, p', a') with p'=jp/4... NOTE output index is
// out[bc*100 + (jp>>2)*10 + a]; jp&3 is the s' being averaged.
// ---------------------------------------------------------------------------
__global__ __launch_bounds__(256) void mi_kernel(const float* __restrict__ filt,
                                                 float* __restrict__ out) {
  __shared__ __align__(16) unsigned int idx32[512];  // 4 bins/dword
  __shared__ float Cp[4][12][19];                    // per-wave partial C
  const int tid = threadIdx.x;
  const int wave = tid >> 6;
  const int lane = tid & 63;
  const int blk = blockIdx.x;           // bc*40 + jp
  const int bc = blk / 40, jp = blk % 40;
  const float* ph = filt + ((size_t)(bc * 4 + jp / 10) * NF + (jp % 10)) * TT;
  for (int g = tid; g < 512; g += 256) {
    float4 v = *(const float4*)&ph[4 * g];
    float vv[4] = {v.x, v.y, v.z, v.w};
    unsigned int packed = 0;
#pragma unroll
    for (int j = 0; j < 4; ++j) {
      int b = (int)floorf((vv[j] + 3.14159274f) / 6.2831855f * 18.0f);
      b = b < 0 ? 0 : (b > 17 ? 17 : b);
      packed |= ((unsigned int)b) << (8 * j);
    }
    idx32[g] = packed;
  }
  __syncthreads();
  const int n16 = lane & 15;    // A row m / B col n / C col
  const int quad = lane >> 4;   // k-quad (0..3)
  const int aband = n16 < 10 ? n16 : 9;
  const int ja = (jp & 3) + 4 * aband;   // scrambled amp row, same s'
  const float* aptr = filt + ((size_t)(bc * 4 + ja / 10) * NF + 10 + (ja % 10)) * TT
                      + quad * 8;
  const bool isAmp = (n16 < 10);
  const bool isOne = (n16 == 10);
  f32x4 acc0 = {0.f, 0.f, 0.f, 0.f};     // bins 0..15
  f32x4 acc1 = {0.f, 0.f, 0.f, 0.f};     // bins 16..17 (cols 16+n16)
  const int s0 = wave * 16, s1 = s0 + 16;
  float4 p0 = *(const float4*)(aptr + s0 * 32);
  float4 p1 = *(const float4*)(aptr + s0 * 32 + 4);
  for (int s = s0; s < s1; ++s) {
    float4 c0 = p0, c1 = p1;
    if (s < s1 - 1) {
      p0 = *(const float4*)(aptr + (s + 1) * 32);
      p1 = *(const float4*)(aptr + (s + 1) * 32 + 4);
    }
    float a[8] = {c0.x, c0.y, c0.z, c0.w, c1.x, c1.y, c1.z, c1.w};
    short8 ah, am_, al;
#pragma unroll
    for (int j = 0; j < 8; ++j) {
      float v = isAmp ? a[j] : (isOne ? 1.0f : 0.0f);
      unsigned int u = __float_as_uint(v);
      float h = __uint_as_float(u & 0xFFFF0000u);
      float r1 = v - h;                       // exact (<=16 sig bits)
      unsigned int u2 = __float_as_uint(r1);
      float md = __uint_as_float(u2 & 0xFFFF0000u);
      float r2 = r1 - md;                     // exact (<=8 sig bits)
      unsigned int u3 = __float_as_uint(r2);
      ah[j] = (short)(u >> 16);
      am_[j] = (short)(u2 >> 16);
      al[j] = (short)(u3 >> 16);
    }
    const int dw = s * 8 + quad * 2;
    unsigned int d0 = idx32[dw], d1 = idx32[dw + 1];
    short8 b0, b1;
#pragma unroll
    for (int j = 0; j < 8; ++j) {
      unsigned int byte = ((j < 4 ? d0 : d1) >> ((j & 3) * 8)) & 0xFFu;
      b0[j] = (byte == (unsigned int)n16) ? (short)0x3F80 : (short)0;
      b1[j] = (byte == (unsigned int)(n16 + 16)) ? (short)0x3F80 : (short)0;
    }
    acc0 = __builtin_amdgcn_mfma_f32_16x16x32_bf16(ah, b0, acc0, 0, 0, 0);
    acc0 = __builtin_amdgcn_mfma_f32_16x16x32_bf16(am_, b0, acc0, 0, 0, 0);
    acc0 = __builtin_amdgcn_mfma_f32_16x16x32_bf16(al, b0, acc0, 0, 0, 0);
    acc1 = __builtin_amdgcn_mfma_f32_16x16x32_bf16(ah, b1, acc1, 0, 0, 0);
    acc1 = __builtin_amdgcn_mfma_f32_16x16x32_bf16(am_, b1, acc1, 0, 0, 0);
    acc1 = __builtin_amdgcn_mfma_f32_16x16x32_bf16(al, b1, acc1, 0, 0, 0);
  }
#pragma unroll
  for (int r = 0; r < 4; ++r) {
    int row = quad * 4 + r;
    if (row < 11) {
      Cp[wave][row][n16] = acc0[r];
      if (n16 < 2) Cp[wave][row][16 + n16] = acc1[r];
    }
  }
  __syncthreads();
  if (tid < 10) {
    float tot = 0.f, mb_[18];
#pragma unroll
    for (int b = 0; b < 18; ++b) {
      float s = Cp[0][tid][b] + Cp[1][tid][b] + Cp[2][tid][b] + Cp[3][tid][b];
      float c = Cp[0][10][b] + Cp[1][10][b] + Cp[2][10][b] + Cp[3][10][b];
      float mb = s / fmaxf(c, 1.0f);
      mb_[b] = mb; tot += mb;
    }
    tot = fmaxf(tot, 1e-12f);
    float s = 0.f;
#pragma unroll
    for (int b = 0; b < 18; ++b) {
      float pb = mb_[b] / tot;
      s += pb * logf(fmaxf(pb, 1e-12f));
    }
    const float LOGN = 2.8903717578961645f; // log(18)
    // s'-mean folded in: out index (bc, p'=jp>>2, a'=tid)
    atomicAdd(&out[bc * 100 + (jp >> 2) * 10 + tid],
              0.25f * (LOGN + s) / LOGN);
  }
}

extern "C" void kernel_launch(void* const* d_in, const int* in_sizes, int n_in,
                              void* d_out, int out_size, void* d_ws, size_t ws_size,
                              hipStream_t stream) {
  (void)in_sizes; (void)n_in; (void)out_size; (void)ws_size;
  const float* x = (const float*)d_in[0];     // (4,8,4,2048) fp32
  const float* ker = (const float*)d_in[1];   // (20,769) fp32
  float* out = (float*)d_out;                 // 3200 fp32
  float* filt = (float*)d_ws;                 // 128*20*2048 fp32 (~21 MB)
  float2* tw = (float2*)(filt + (size_t)NS * NF * TT);  // 2048 float2 (16 KB)
  float* hsym = (float*)(tw + TT);            // 20*784 fp32
  int* rng = (int*)(hsym + NF * 784);         // 40 ints

  prep_kernel<<<28, 256, 0, stream>>>(ker, tw, hsym, rng, out);
  convhil_kernel<<<NS * 10, 256, 0, stream>>>(x, hsym, rng, tw, filt);
  mi_kernel<<<32 * 40, 256, 0, stream>>>(filt, out);
}